// Round 2
// baseline (243.160 us; speedup 1.0000x reference)
//
#include <hip/hip_runtime.h>
#include <stdint.h>

// Problem constants (fixed by the reference setup)
#define BB 2
#define NN 10000
#define EE 100000
#define FF 512
#define HH 512
constexpr int M_ROWS = BB * NN;   // 20000 GEMM rows
constexpr int M_PAD  = 20160;     // padded (staging may read up to row 20031)
constexpr int BE     = BB * EE;   // 200000 edges total
constexpr int BNN    = BB * NN;   // 20000 segments

typedef __attribute__((ext_vector_type(8))) short short8;   // 8 bf16 (4 VGPRs)
typedef __attribute__((ext_vector_type(4))) float f32x4;    // MFMA accumulator
typedef __attribute__((ext_vector_type(2))) float f32x2;
typedef _Float16 half2v __attribute__((ext_vector_type(2)));

#define AS1 __attribute__((address_space(1)))
#define AS3 __attribute__((address_space(3)))

__device__ __forceinline__ float b2f(unsigned short u) {
    union { unsigned int i; float f; } v; v.i = ((unsigned int)u) << 16; return v.f;
}
__device__ __forceinline__ unsigned short f2b(float f) {   // round-to-nearest-even
    unsigned int x = __float_as_uint(f);
    x += 0x7fffu + ((x >> 16) & 1u);
    return (unsigned short)(x >> 16);
}
__device__ __forceinline__ unsigned char f2fp8(float v) {
    unsigned int p = __builtin_amdgcn_cvt_pk_fp8_f32(v, v, 0u, false);
    return (unsigned char)(p & 0xffu);
}
__device__ __forceinline__ half2v uint2h2(unsigned int u) {
    union { unsigned int u; half2v h; } v; v.u = u; return v.h;
}

// fp8(e4m3) pair -> f16 pair. sel=false: bytes[1:0], sel=true: bytes[3:2].
#if __has_builtin(__builtin_amdgcn_cvt_scalef32_pk_f16_fp8)
  #define CVT8H(u, sel) __builtin_amdgcn_cvt_scalef32_pk_f16_fp8((u), 1.0f, (sel))
#else
  #define CVT8H(u, sel) ({ f32x2 _p = __builtin_amdgcn_cvt_pk_f32_fp8((u), (sel)); \
                           (half2v){(_Float16)_p.x, (_Float16)_p.y}; })
#endif

#if __has_builtin(__builtin_amdgcn_fdot2)
  #define FDOT2(a, b, c) __builtin_amdgcn_fdot2((a), (b), (c), false)
#else
  #define FDOT2(a, b, c) ((float)(a).x * (float)(b).x + (float)(a).y * (float)(b).y + (c))
#endif

// ---------------- dtype detection (parallel: 64 lanes, shuffle reduce) ----------------
// flag = 1 -> inputs/outputs are float32; flag = 0 -> bfloat16.
__global__ void detect_k(const unsigned short* __restrict__ x, int* __restrict__ flag) {
    int t = threadIdx.x;              // 0..63
    int good = 0;
#pragma unroll
    for (int j = 0; j < 2; j++) {
        unsigned short u = x[2 * (t * 2 + j)];
        int e = (u >> 7) & 0xFF;
        if (e >= 100 && e <= 140) good++;
    }
#pragma unroll
    for (int off = 32; off >= 1; off >>= 1) good += __shfl_xor(good, off, 64);
    if (t == 0) *flag = (good < 96) ? 1 : 0;
}

// ---------------- canonicalize X to bf16 (8 elems/thread) ----------------
__global__ __launch_bounds__(256) void convertX_k(const void* __restrict__ Xraw,
                                                  const int* __restrict__ flag,
                                                  unsigned short* __restrict__ Xb, int n) {
    int i = (blockIdx.x * 256 + threadIdx.x) * 8;
    if (i >= n) return;
    short8 o;
    if (*flag) {
        const float4* f = (const float4*)((const float*)Xraw + i);
        float4 a = f[0], b = f[1];
        o[0] = (short)f2b(a.x); o[1] = (short)f2b(a.y);
        o[2] = (short)f2b(a.z); o[3] = (short)f2b(a.w);
        o[4] = (short)f2b(b.x); o[5] = (short)f2b(b.y);
        o[6] = (short)f2b(b.z); o[7] = (short)f2b(b.w);
    } else {
        o = *(const short8*)((const unsigned short*)Xraw + i);
    }
    *(short8*)(Xb + i) = o;
}

// ---------------- canonicalize small params to bf16 (+ W3 as f16) ----------------
// P layout (ushort): b1@0 g1@512 bb1@1024 b2@1536 g2@2048 bb2@2560 W3(bf16)@3072
// W4@3584 b4@3585 | W3(f16)@3600..4111  (3600*2 bytes = 16B aligned)
__global__ __launch_bounds__(256) void convertP_k(
    const void* b1, const void* g1, const void* bb1,
    const void* b2, const void* g2, const void* bb2,
    const void* W3, const void* W4, const void* b4,
    const int* __restrict__ flag, unsigned short* __restrict__ P)
{
    int i = blockIdx.x * 256 + threadIdx.x;
    if (i >= 4098) return;
    if (i >= 3586) {                       // W3 -> f16 copy for edge_k dot2
        int j = i - 3586;                  // 0..511
        float f;
        if (*flag) f = ((const float*)W3)[j];
        else       f = b2f(((const unsigned short*)W3)[j]);
        union { _Float16 h; unsigned short u; } cv;
        cv.h = (_Float16)f;
        P[3600 + j] = cv.u;
        return;
    }
    const void* src; int off;
    if      (i < 512)  { src = b1;  off = i; }
    else if (i < 1024) { src = g1;  off = i - 512; }
    else if (i < 1536) { src = bb1; off = i - 1024; }
    else if (i < 2048) { src = b2;  off = i - 1536; }
    else if (i < 2560) { src = g2;  off = i - 2048; }
    else if (i < 3072) { src = bb2; off = i - 2560; }
    else if (i < 3584) { src = W3;  off = i - 3072; }
    else if (i == 3584){ src = W4;  off = 0; }
    else               { src = b4;  off = 0; }
    unsigned short v;
    if (*flag) v = f2b(((const float*)src)[off]);
    else       v = ((const unsigned short*)src)[off];
    P[i] = v;
}

// ---------------- transpose W (512x512, two matrices) -> WT[n][k] bf16 ----------------
__global__ __launch_bounds__(256) void transpose_k(const void* __restrict__ W1,
                                                   const void* __restrict__ W2,
                                                   const int* __restrict__ flag,
                                                   unsigned short* __restrict__ T1,
                                                   unsigned short* __restrict__ T2) {
    __shared__ unsigned short t[32][33];
    const void*     W = blockIdx.z ? W2 : W1;
    unsigned short* T = blockIdx.z ? T2 : T1;
    const int isf = *flag;
    int tx = threadIdx.x & 31, ty = threadIdx.x >> 5;   // 32 x 8
    int n0 = blockIdx.x * 32, k0 = blockIdx.y * 32;
#pragma unroll
    for (int r = 0; r < 4; r++) {
        int k = k0 + ty + r * 8;
        unsigned short v;
        if (isf) v = f2b(((const float*)W)[k * 512 + n0 + tx]);
        else     v = ((const unsigned short*)W)[k * 512 + n0 + tx];
        t[ty + r * 8][tx] = v;
    }
    __syncthreads();
#pragma unroll
    for (int r = 0; r < 4; r++) {
        int n = n0 + ty + r * 8;
        T[n * 512 + k0 + tx] = t[tx][ty + r * 8];
    }
}

// ---------------- zero-init ----------------
__global__ __launch_bounds__(256) void zero_k(float* __restrict__ p, int n) {
    int i = blockIdx.x * 256 + threadIdx.x;
    if (i < n) p[i] = 0.f;
}

// ---------------- fused GEMM (X @ W) + bias + LayerNorm -> a12 (fp8 e4m3) ----------------
// v8: the v7 160x512 monolith was ONE 8-wave barrier-locked block per CU (LDS 131KB,
// ~240 regs/wave) -- MfmaUtil 12%, VALU 16%, occupancy 19%: every K-iter the whole
// CU convoys on the vmcnt drain with no co-resident work to hide it (m97's lesson:
// its 874 TF came from ~3 independent blocks/CU). v8 retiles BM=64 so TWO
// independent blocks fit per CU: acc[2][8]=64 VGPR/wave (launch_bounds(512,4)
// caps 128 -> 4 waves/SIMD), LDS 72KB double-buffer + 2KB red -> 2 blocks/CU.
// 2-barrier/iter schedule: drain(counted)->barrier->ds_read->lgkmcnt->barrier->
// stage(it+2)->MFMA. Grid 626 (313 x 2 sel) with bijective XCD swizzle pairing
// (x,sel0)/(x,sel1) on the same XCD so each A-panel is fetched ~once per XCD.
__global__ __launch_bounds__(512, 4) void gemm_ln8_k(
    const unsigned short* __restrict__ X,     // M_PAD x 512 (canonical bf16)
    const unsigned short* __restrict__ WT1,   // 512(n) x 512(k)  (pre-transposed bf16)
    const unsigned short* __restrict__ WT2,
    const unsigned short* __restrict__ bia1, const unsigned short* __restrict__ gg1, const unsigned short* __restrict__ sh1,
    const unsigned short* __restrict__ bia2, const unsigned short* __restrict__ gg2, const unsigned short* __restrict__ sh2,
    unsigned char* __restrict__ a12)          // 20000 x 1024 fp8 (a1 | a2)
{
    __shared__ __align__(16) unsigned short S[36864];  // 72 KB: A 2x4096B @0, B 2x32768B @8192; epilogue reuses as 64x528 byte tile
    __shared__ float red[64][4][2];

    // bijective XCD swizzle over 626 blocks (q=78, r=2): consecutive logical ids
    // stay on one XCD -> (x,sel=0) and (x,sel=1) share the XCD's L2 copy of the A panel.
    const int phys = blockIdx.x;
    const int xcd  = phys & 7, kq = phys >> 3;
    const int lg   = (xcd < 2 ? xcd * 79 : 158 + (xcd - 2) * 78) + kq;
    const int sel  = lg & 1;
    const int r0   = (lg >> 1) * 64;

    const unsigned short* WT  = sel ? WT2 : WT1;
    const unsigned short* bia = sel ? bia2 : bia1;
    const unsigned short* gg  = sel ? gg2 : gg1;
    const unsigned short* sh  = sel ? sh2 : sh1;
    const int tid  = threadIdx.x;
    const int lane = tid & 63;
    const int w    = tid >> 6;      // 0..7
    const int mg   = w >> 2;        // 0..1  (32-row group)
    const int ng   = w & 3;         // 0..3  (128-col group)
    const int aq   = lane >> 4;     // 0..3
    const int l15  = lane & 15;

    AS3 char* S3 = (AS3 char*)S;
    const unsigned sb = (unsigned)(unsigned long long)S3;

    f32x4 acc[2][8];
#pragma unroll
    for (int i = 0; i < 2; i++)
#pragma unroll
        for (int j = 0; j < 8; j++) acc[i][j] = (f32x4){0.f, 0.f, 0.f, 0.f};

    // A staging: 256 slots (16B each), threads 0..255: r = tid>>2, kc = (tid&3)^swz.
    const int a_r1 = tid >> 2;
    const int a_k1 = (tid & 3) ^ ((a_r1 >> 1) & 3);
    const unsigned short* a_g1 = X + (size_t)(r0 + a_r1) * 512 + a_k1 * 8;
    // B staging: 2048 slots, 4/thread: n = u*128 + (tid>>2), kc = tid&3
    const int b_n0 = tid >> 2;
    const int b_kc = tid & 3;

    auto stage = [&](int kt) {               // stage k-chunk kt into buffer kt&1
        const int jj = kt & 1;
        const int k0 = kt * 32;
        if (tid < 256)
            __builtin_amdgcn_global_load_lds((const AS1 void*)(a_g1 + k0),
                                             (AS3 void*)(S3 + jj * 4096 + tid * 16), 16, 0, 0);
#pragma unroll
        for (int u = 0; u < 4; u++) {
            int n   = u * 128 + b_n0;
            int kcs = b_kc ^ ((n >> 1) & 3);
            __builtin_amdgcn_global_load_lds((const AS1 void*)(WT + n * 512 + k0 + kcs * 8),
                                             (AS3 void*)(S3 + 8192 + jj * 32768 + (u * 512 + tid) * 16), 16, 0, 0);
        }
    };

    stage(0);
    stage(1);

    for (int it = 0; it < 16; ++it) {
        // drain the oldest batch only (waves 0-3 issue 5 loads/batch, waves 4-7 issue 4)
        if (it < 15) {
            if (w < 4) asm volatile("s_waitcnt vmcnt(5)\n\ts_barrier" ::: "memory");
            else       asm volatile("s_waitcnt vmcnt(4)\n\ts_barrier" ::: "memory");
        } else {
            asm volatile("s_waitcnt vmcnt(0)\n\ts_barrier" ::: "memory");
        }

        const unsigned Ab = sb + (unsigned)((it & 1) * 4096);
        const unsigned Bb = sb + 8192u + (unsigned)((it & 1) * 32768);
        short8 af[2], bf[8];
#pragma unroll
        for (int mt = 0; mt < 2; mt++) {
            int m = mg * 32 + mt * 16 + l15;
            unsigned off = Ab + (unsigned)(m * 64 + (aq ^ ((m >> 1) & 3)) * 16);
            asm volatile("ds_read_b128 %0, %1" : "=v"(af[mt]) : "v"(off));
        }
#pragma unroll
        for (int nt = 0; nt < 8; nt++) {
            int n = ng * 128 + nt * 16 + l15;
            unsigned off = Bb + (unsigned)(n * 64 + (aq ^ ((n >> 1) & 3)) * 16);
            asm volatile("ds_read_b128 %0, %1" : "=v"(bf[nt]) : "v"(off));
        }
        asm volatile("s_waitcnt lgkmcnt(0)"
                     : "+v"(af[0]), "+v"(af[1]),
                       "+v"(bf[0]), "+v"(bf[1]), "+v"(bf[2]), "+v"(bf[3]),
                       "+v"(bf[4]), "+v"(bf[5]), "+v"(bf[6]), "+v"(bf[7]) :: "memory");
        __builtin_amdgcn_s_barrier();        // all waves' reads done -> buffer reusable
        if (it + 2 < 16) stage(it + 2);      // overwrite the buffer we just consumed
#pragma unroll
        for (int nt = 0; nt < 8; nt++)
#pragma unroll
            for (int mt = 0; mt < 2; mt++)
                acc[mt][nt] = __builtin_amdgcn_mfma_f32_16x16x32_bf16(af[mt], bf[nt], acc[mt][nt], 0, 0, 0);
    }

    // ---- epilogue: bias + LayerNorm + fp8 store via byte LDS tile ----
    float bcol[8], gcol[8], shcol[8];
#pragma unroll
    for (int nt = 0; nt < 8; nt++) {
        int col = ng * 128 + nt * 16 + l15;
        bcol[nt]  = b2f(bia[col]);
        gcol[nt]  = b2f(gg[col]);
        shcol[nt] = b2f(sh[col]);
    }
#pragma unroll
    for (int mt = 0; mt < 2; mt++)
#pragma unroll
        for (int nt = 0; nt < 8; nt++)
#pragma unroll
            for (int r = 0; r < 4; r++) acc[mt][nt][r] += bcol[nt];

#pragma unroll
    for (int mt = 0; mt < 2; mt++)
#pragma unroll
        for (int r = 0; r < 4; r++) {
            float s = 0.f, q = 0.f;
#pragma unroll
            for (int nt = 0; nt < 8; nt++) { float x = acc[mt][nt][r]; s += x; q += x * x; }
#pragma unroll
            for (int off = 1; off < 16; off <<= 1) {
                s += __shfl_xor(s, off, 64);
                q += __shfl_xor(q, off, 64);
            }
            if (l15 == 0) {
                int row = mg * 32 + mt * 16 + aq * 4 + r;
                red[row][ng][0] = s;
                red[row][ng][1] = q;
            }
        }
    __syncthreads();   // red complete; K-loop's trailing barrier already freed S

    float mean_[2][4], rstd_[2][4];
#pragma unroll
    for (int mt = 0; mt < 2; mt++)
#pragma unroll
        for (int r = 0; r < 4; r++) {
            int row = mg * 32 + mt * 16 + aq * 4 + r;
            float s = red[row][0][0] + red[row][1][0] + red[row][2][0] + red[row][3][0];
            float q = red[row][0][1] + red[row][1][1] + red[row][2][1] + red[row][3][1];
            float mu  = s * (1.f / 512.f);
            float var = q * (1.f / 512.f) - mu * mu;
            mean_[mt][r] = mu;
            rstd_[mt][r] = rsqrtf(var + 1e-5f);
        }

    // fp8 values -> 64x528 byte tile (stride 528 = 16B-aligned), then coalesced stores
    unsigned char* ot8 = (unsigned char*)S;
#pragma unroll
    for (int mt = 0; mt < 2; mt++)
#pragma unroll
        for (int nt = 0; nt < 8; nt++)
#pragma unroll
            for (int r = 0; r < 4; r++) {
                int row = mg * 32 + mt * 16 + aq * 4 + r;
                int col = ng * 128 + nt * 16 + l15;
                float v = (acc[mt][nt][r] - mean_[mt][r]) * rstd_[mt][r] * gcol[nt] + shcol[nt];
                ot8[row * 528 + col] = f2fp8(v);
            }
    __syncthreads();

    unsigned char* obase = a12 + sel * 512;
#pragma unroll
    for (int u = 0; u < 4; u++) {
        int ci  = u * 512 + tid;             // 2048 chunks of 16 fp8
        int row = ci >> 5, cc = (ci & 31) * 16;
        int gr  = r0 + row;
        if (gr < M_ROWS) {
            uint4 vch = *(const uint4*)(ot8 + row * 528 + cc);
            *(uint4*)(obase + (size_t)gr * 1024 + cc) = vch;
        }
    }
}

// ---------------- per-edge: fp8 gather, packed-f16 Z dots, fused exp + segment sums ----
// Two edges per wave (half-wave each). Per lane: 16 fp8 elems per vector, decode
// straight to f16 (exact: e4m3 c f16), v_pk_add_f16 + v_pk_max_f16 for
// relu(a1i+a2j), v_dot2_f32_f16 against pre-converted f16 W3 (f32 accumulate).
// Max-free softmax (v in [0,~0.25] -> exp(v)/sum exact).
__global__ __launch_bounds__(256) void edge_k(
    const unsigned char* __restrict__ a12,   // fp8 rows: 1024 B/node
    const int* __restrict__ eidx,            // (B, 2, E)
    const unsigned short* __restrict__ W3h,  // f16[512]
    const unsigned short* __restrict__ W4,
    const unsigned short* __restrict__ b4p,
    float* __restrict__ Vij, float* __restrict__ Vji,
    float* __restrict__ sumI, float* __restrict__ sumJ)
{
    int gw    = (blockIdx.x * 256 + threadIdx.x) >> 6;  // wave id: 2 edges/wave
    int lane  = threadIdx.x & 63;
    int which = lane >> 5;                              // 0/1: edge within wave
    int l     = lane & 31;
    int ge    = gw * 2 + which;
    if (ge >= BE) return;
    int b   = ge / EE, e = ge - b * EE;
    int src = eidx[b * 2 * EE + e];
    int dst = eidx[b * 2 * EE + EE + e];
    const unsigned char* rs = a12 + (size_t)(b * NN + src) * 1024;
    const unsigned char* rd = a12 + (size_t)(b * NN + dst) * 1024;
    int o = l * 16;                                     // 16 fp8 elems per lane/vector
    uint4 u1s = *(const uint4*)(rs + o);
    uint4 u2s = *(const uint4*)(rs + 512 + o);
    uint4 u1d = *(const uint4*)(rd + o);
    uint4 u2d = *(const uint4*)(rd + 512 + o);
    uint4 w3a = *(const uint4*)(W3h + l * 16);          // 16 f16 = 32B
    uint4 w3b = *(const uint4*)(W3h + l * 16 + 8);

    const unsigned int U1S[4] = {u1s.x, u1s.y, u1s.z, u1s.w};
    const unsigned int U2S[4] = {u2s.x, u2s.y, u2s.z, u2s.w};
    const unsigned int U1D[4] = {u1d.x, u1d.y, u1d.z, u1d.w};
    const unsigned int U2D[4] = {u2d.x, u2d.y, u2d.z, u2d.w};
    const unsigned int W3W[8] = {w3a.x, w3a.y, w3a.z, w3a.w, w3b.x, w3b.y, w3b.z, w3b.w};
    const half2v HZ = {(_Float16)0.f, (_Float16)0.f};

    float zij = 0.f, zji = 0.f;
#define EDGE_STEP(WI, I, SEL)                                        \
    {                                                                \
        half2v wv  = uint2h2(W3W[WI]);                               \
        half2v x1s = CVT8H(U1S[I], SEL);                             \
        half2v x2s = CVT8H(U2S[I], SEL);                             \
        half2v x1d = CVT8H(U1D[I], SEL);                             \
        half2v x2d = CVT8H(U2D[I], SEL);                             \
        half2v pij = __builtin_elementwise_max(x1s + x2d, HZ);       \
        half2v pji = __builtin_elementwise_max(x1d + x2s, HZ);       \
        zij = FDOT2(pij, wv, zij);                                   \
        zji = FDOT2(pji, wv, zji);                                   \
    }
    EDGE_STEP(0, 0, false)
    EDGE_STEP(1, 0, true)
    EDGE_STEP(2, 1, false)
    EDGE_STEP(3, 1, true)
    EDGE_STEP(4, 2, false)
    EDGE_STEP(5, 2, true)
    EDGE_STEP(6, 3, false)
    EDGE_STEP(7, 3, true)
#undef EDGE_STEP

#pragma unroll
    for (int off = 16; off >= 1; off >>= 1) {           // reduce within each half-wave
        zij += __shfl_xor(zij, off, 64);
        zji += __shfl_xor(zji, off, 64);
    }
    if (l == 0) {                                       // lanes 0 and 32: one edge each
        float w4f = b2f(W4[0]);
        float b4f = b2f(b4p[0]);
        float d   = zij - zji;                          // b3 cancels exactly
        float vij = fmaf(d, w4f, b4f);  vij = vij > 0.f ? vij : 0.f;
        float vji = fmaf(-d, w4f, b4f); vji = vji > 0.f ? vji : 0.f;
        float eij = expf(vij), eji = expf(vji);
        Vij[ge] = eij;
        Vji[ge] = eji;
        atomicAdd(sumI + b * NN + src, eij);
        atomicAdd(sumJ + b * NN + dst, eji);
    }
}

// ---------------- softmax final: normalize -> bf16 or f32 out ----------------
__global__ __launch_bounds__(256) void norm_k(
    const float* __restrict__ V, const int* __restrict__ eidx,
    const float* __restrict__ sumI, const float* __restrict__ sumJ,
    const int* __restrict__ flag, void* __restrict__ out)
{
    int i = blockIdx.x * 256 + threadIdx.x;
    if (i >= 2 * BE) return;
    int seg; const float* sm;
    if (i < BE) {
        int b = i / EE, e = i - b * EE;
        seg = b * NN + eidx[b * 2 * EE + e];
        sm = sumI;
    } else {
        int j = i - BE;
        int b = j / EE, e = j - b * EE;
        seg = b * NN + eidx[b * 2 * EE + EE + e];
        sm = sumJ;
    }
    float v = V[i] / sm[seg];
    if (*flag) ((float*)out)[i] = v;
    else       ((unsigned short*)out)[i] = f2b(v);
}

extern "C" void kernel_launch(void* const* d_in, const int* in_sizes, int n_in,
                              void* d_out, int out_size, void* d_ws, size_t ws_size,
                              hipStream_t stream)
{
    (void)in_sizes; (void)n_in; (void)out_size; (void)ws_size;
    const void* X_raw = d_in[0];
    const int*  eix   = (const int*)d_in[1];
    const void* W1    = d_in[3];
    const void* b1    = d_in[4];
    const void* g1    = d_in[5];
    const void* bb1   = d_in[6];
    const void* W2    = d_in[7];
    const void* b2    = d_in[8];
    const void* g2    = d_in[9];
    const void* bb2   = d_in[10];
    const void* W3    = d_in[11];
    const void* W4    = d_in[13];
    const void* b4    = d_in[14];

    char* ws = (char*)d_ws;
    size_t off = 0;
    int* flag = (int*)(ws + off);                        off += 16;
    unsigned char*  a12 = (unsigned char*)(ws + off);    off += (size_t)M_ROWS * 1024;     // 20.48 MB fp8
    unsigned short* Xb  = (unsigned short*)(ws + off);   off += (size_t)M_PAD * 512 * 2;   // 20.6 MB
    unsigned short* T1  = (unsigned short*)(ws + off);   off += (size_t)512 * 512 * 2;
    unsigned short* T2  = (unsigned short*)(ws + off);   off += (size_t)512 * 512 * 2;
    unsigned short* P   = (unsigned short*)(ws + off);   off += 16384;                     // params + f16 W3
    float* Vbuf = (float*)(ws + off);                    off += (size_t)2 * BE * 4;
    float* Z    = (float*)(ws + off);                    off += (size_t)2 * BNN * 4;
    float* sumI = Z;
    float* sumJ = Z + BNN;

    detect_k<<<1, 64, 0, stream>>>((const unsigned short*)X_raw, flag);
    convertX_k<<<(M_ROWS * 512 / 8 + 255) / 256, 256, 0, stream>>>(X_raw, flag, Xb, M_ROWS * 512);
    convertP_k<<<17, 256, 0, stream>>>(b1, g1, bb1, b2, g2, bb2, W3, W4, b4, flag, P);
    transpose_k<<<dim3(16, 16, 2), 256, 0, stream>>>(W1, W2, flag, T1, T2);
    zero_k<<<(2 * BNN + 255) / 256, 256, 0, stream>>>(Z, 2 * BNN);
    gemm_ln8_k<<<dim3(626), 512, 0, stream>>>(Xb, T1, T2,
                                              P, P + 512, P + 1024,
                                              P + 1536, P + 2048, P + 2560, a12);
    edge_k<<<BE / 8, 256, 0, stream>>>(a12, eix, P + 3600, P + 3584, P + 3585,
                                       Vbuf, Vbuf + BE, sumI, sumJ);
    norm_k<<<(2 * BE + 255) / 256, 256, 0, stream>>>(Vbuf, eix, sumI, sumJ, flag, (unsigned short*)d_out);
}

// Round 3
// 217.557 us; speedup vs baseline: 1.1177x; 1.1177x over previous
//
#include <hip/hip_runtime.h>
#include <stdint.h>

// Problem constants (fixed by the reference setup)
#define BB 2
#define NN 10000
#define EE 100000
#define FF 512
#define HH 512
constexpr int M_ROWS = BB * NN;   // 20000 GEMM rows
constexpr int M_PAD  = 20160;     // padded to multiple of 160 (126 blocks/sel)
constexpr int BE     = BB * EE;   // 200000 edges total
constexpr int BNN    = BB * NN;   // 20000 segments

typedef __attribute__((ext_vector_type(8))) short short8;   // 8 bf16 (4 VGPRs)
typedef __attribute__((ext_vector_type(4))) float f32x4;    // MFMA accumulator
typedef __attribute__((ext_vector_type(2))) float f32x2;
typedef _Float16 half2v __attribute__((ext_vector_type(2)));

#define AS1 __attribute__((address_space(1)))
#define AS3 __attribute__((address_space(3)))

__device__ __forceinline__ float b2f(unsigned short u) {
    union { unsigned int i; float f; } v; v.i = ((unsigned int)u) << 16; return v.f;
}
__device__ __forceinline__ unsigned short f2b(float f) {   // round-to-nearest-even
    unsigned int x = __float_as_uint(f);
    x += 0x7fffu + ((x >> 16) & 1u);
    return (unsigned short)(x >> 16);
}
__device__ __forceinline__ unsigned char f2fp8(float v) {
    unsigned int p = __builtin_amdgcn_cvt_pk_fp8_f32(v, v, 0u, false);
    return (unsigned char)(p & 0xffu);
}
__device__ __forceinline__ half2v uint2h2(unsigned int u) {
    union { unsigned int u; half2v h; } v; v.u = u; return v.h;
}

// fp8(e4m3) pair -> f16 pair. sel=false: bytes[1:0], sel=true: bytes[3:2].
#if __has_builtin(__builtin_amdgcn_cvt_scalef32_pk_f16_fp8)
  #define CVT8H(u, sel) __builtin_amdgcn_cvt_scalef32_pk_f16_fp8((u), 1.0f, (sel))
#else
  #define CVT8H(u, sel) ({ f32x2 _p = __builtin_amdgcn_cvt_pk_f32_fp8((u), (sel)); \
                           (half2v){(_Float16)_p.x, (_Float16)_p.y}; })
#endif

#if __has_builtin(__builtin_amdgcn_fdot2)
  #define FDOT2(a, b, c) __builtin_amdgcn_fdot2((a), (b), (c), false)
#else
  #define FDOT2(a, b, c) ((float)(a).x * (float)(b).x + (float)(a).y * (float)(b).y + (c))
#endif

// ---------------- fused front-end: detect + convertX + transpose + params + zero ------
// One dispatch replaces five. Every block recomputes the dtype flag inline (reads
// 510 B of X, wave-0 shuffle reduce -> LDS broadcast): no cross-dispatch dependency.
// Block ranges:  [0,5000)   convertX (f32 path only; early-exit when input is bf16)
//                [5000,5512) W1/W2 transpose (32x32 tiles, 2 mats)
//                [5512,5529) param canonicalization (P layout below)
//                [5529,5686) zero segment-sum buffer
// P layout (ushort): b1@0 g1@512 bb1@1024 b2@1536 g2@2048 bb2@2560 W3(bf16)@3072
// W4@3584 b4@3585 | W3(f16)@3600..4111
constexpr int PREP_CX = 5000;
constexpr int PREP_TR = PREP_CX + 512;
constexpr int PREP_CP = PREP_TR + 17;
constexpr int PREP_NB = PREP_CP + 157;
__global__ __launch_bounds__(256) void prep_k(
    const void* __restrict__ Xraw,
    const void* __restrict__ W1, const void* __restrict__ W2,
    const void* b1, const void* g1, const void* bb1,
    const void* b2, const void* g2, const void* bb2,
    const void* W3, const void* W4, const void* b4,
    int* __restrict__ flag, unsigned short* __restrict__ Xb,
    unsigned short* __restrict__ T1, unsigned short* __restrict__ T2,
    unsigned short* __restrict__ P, float* __restrict__ Z)
{
    __shared__ int sflag;
    __shared__ unsigned short t[32][33];
    const int tid = threadIdx.x;
    const int bid = blockIdx.x;

    if (tid < 64) {                       // wave 0: dtype detect (same rule as before)
        const unsigned short* x = (const unsigned short*)Xraw;
        int good = 0;
#pragma unroll
        for (int j = 0; j < 2; j++) {
            unsigned short u = x[2 * (tid * 2 + j)];
            int e = (u >> 7) & 0xFF;
            if (e >= 100 && e <= 140) good++;
        }
#pragma unroll
        for (int off = 32; off >= 1; off >>= 1) good += __shfl_xor(good, off, 64);
        if (tid == 0) sflag = (good < 96) ? 1 : 0;
    }
    __syncthreads();
    const int isf = sflag;
    if (bid == 0 && tid == 0) *flag = isf;

    if (bid < PREP_CX) {                  // ---- convertX: only needed for f32 input
        if (!isf) return;                 // bf16 input: gemm reads X_raw directly
        int i = (bid * 256 + tid) * 8;
        if (i >= M_ROWS * 512) return;
        const float4* f = (const float4*)((const float*)Xraw + i);
        float4 a = f[0], b = f[1];
        short8 o;
        o[0] = (short)f2b(a.x); o[1] = (short)f2b(a.y);
        o[2] = (short)f2b(a.z); o[3] = (short)f2b(a.w);
        o[4] = (short)f2b(b.x); o[5] = (short)f2b(b.y);
        o[6] = (short)f2b(b.z); o[7] = (short)f2b(b.w);
        *(short8*)(Xb + i) = o;
        return;
    }
    if (bid < PREP_TR) {                  // ---- transpose W -> WT[n][k]
        int b2i = bid - PREP_CX;
        int bx = b2i & 15, by = (b2i >> 4) & 15, bz = b2i >> 8;
        const void*     W = bz ? W2 : W1;
        unsigned short* T = bz ? T2 : T1;
        int tx = tid & 31, ty = tid >> 5;   // 32 x 8
        int n0 = bx * 32, k0 = by * 32;
#pragma unroll
        for (int r = 0; r < 4; r++) {
            int k = k0 + ty + r * 8;
            unsigned short v;
            if (isf) v = f2b(((const float*)W)[k * 512 + n0 + tx]);
            else     v = ((const unsigned short*)W)[k * 512 + n0 + tx];
            t[ty + r * 8][tx] = v;
        }
        __syncthreads();
#pragma unroll
        for (int r = 0; r < 4; r++) {
            int n = n0 + ty + r * 8;
            T[n * 512 + k0 + tx] = t[tx][ty + r * 8];
        }
        return;
    }
    if (bid < PREP_CP) {                  // ---- small params
        int i = (bid - PREP_TR) * 256 + tid;
        if (i >= 4098) return;
        if (i >= 3586) {                  // W3 -> f16 copy for edge_k dot2
            int j = i - 3586;             // 0..511
            float f;
            if (isf) f = ((const float*)W3)[j];
            else     f = b2f(((const unsigned short*)W3)[j]);
            union { _Float16 h; unsigned short u; } cv;
            cv.h = (_Float16)f;
            P[3600 + j] = cv.u;
            return;
        }
        const void* src; int off;
        if      (i < 512)  { src = b1;  off = i; }
        else if (i < 1024) { src = g1;  off = i - 512; }
        else if (i < 1536) { src = bb1; off = i - 1024; }
        else if (i < 2048) { src = b2;  off = i - 1536; }
        else if (i < 2560) { src = g2;  off = i - 2048; }
        else if (i < 3072) { src = bb2; off = i - 2560; }
        else if (i < 3584) { src = W3;  off = i - 3072; }
        else if (i == 3584){ src = W4;  off = 0; }
        else               { src = b4;  off = 0; }
        unsigned short v;
        if (isf) v = f2b(((const float*)src)[off]);
        else     v = ((const unsigned short*)src)[off];
        P[i] = v;
        return;
    }
    {                                     // ---- zero segment sums
        int i = (bid - PREP_CP) * 256 + tid;
        if (i < 2 * BNN) Z[i] = 0.f;
    }
}

// ---------------- fused GEMM (X @ W) + bias + LayerNorm -> a12 (fp8 e4m3) ----------------
// v9 = v7 restored (v8's BM=64 2-block/CU retile REGRESSED 64->88 us: per-block time
// is a fixed per-iter latency convoy independent of tile volume, so more blocks only
// added quantization rounds). BM=160, grid 126x2 = 252 blocks <= 256 CUs: ONE round.
// Triple-buffered LDS (A 3x10KB, B 3x32KB), depth-2 prefetch, per-iter counted drain
// vmcnt(6)/vmcnt(5). New in v9: A-source is flag-selected (bf16 input -> read X_raw
// zero-copy, no convertX pass; f32 -> canonical Xb), with A-row clamp to M_ROWS-1 so
// pad-tile staging stays in-bounds for the raw input buffer.
__global__ __launch_bounds__(512, 2) void gemm_ln7_k(
    const unsigned short* __restrict__ Xraw,  // raw input viewed as ushort (bf16 path)
    const unsigned short* __restrict__ Xb,    // canonical bf16 (f32 path)
    const int* __restrict__ flagp,
    const unsigned short* __restrict__ WT1,   // 512(n) x 512(k)  (pre-transposed bf16)
    const unsigned short* __restrict__ WT2,
    const unsigned short* __restrict__ bia1, const unsigned short* __restrict__ gg1, const unsigned short* __restrict__ sh1,
    const unsigned short* __restrict__ bia2, const unsigned short* __restrict__ gg2, const unsigned short* __restrict__ sh2,
    unsigned char* __restrict__ a12)          // 20000 x 1024 fp8 (a1 | a2)
{
    __shared__ __align__(16) unsigned short S[64512];  // 126 KB: A 3x10240B @0, B 3x32768B @30720; epilogue reuses as 160x528 byte tile
    __shared__ float red[160][4][2];

    const int sel = blockIdx.y;
    const unsigned short* WT  = sel ? WT2 : WT1;
    const unsigned short* bia = sel ? bia2 : bia1;
    const unsigned short* gg  = sel ? gg2 : gg1;
    const unsigned short* sh  = sel ? sh2 : sh1;
    const int r0   = blockIdx.x * 160;
    const int tid  = threadIdx.x;
    const int lane = tid & 63;
    const int w    = tid >> 6;      // 0..7
    const int mg   = w >> 2;        // 0..1  (80-row group)
    const int ng   = w & 3;         // 0..3  (128-col group)
    const int aq   = lane >> 4;     // 0..3
    const int l15  = lane & 15;

    const unsigned short* Xsrc = (*flagp) ? Xb : Xraw;

    AS3 char* S3 = (AS3 char*)S;
    const unsigned sb = (unsigned)(unsigned long long)S3;

    f32x4 acc[5][8];
#pragma unroll
    for (int i = 0; i < 5; i++)
#pragma unroll
        for (int j = 0; j < 8; j++) acc[i][j] = (f32x4){0.f, 0.f, 0.f, 0.f};

    // A staging: 640 slots (16B each). slot sid: r = sid>>2, kc = sid&3 (XOR-swizzled).
    // threads 0..511 take sid = tid; threads 0..127 (waves 0-1) also take sid = 512+tid.
    // Global row clamped to M_ROWS-1 (pad rows duplicate row 19999; stores masked).
    const int a_r1 = tid >> 2;
    const int a_k1 = (tid & 3) ^ ((a_r1 >> 1) & 3);
    int r1c = r0 + a_r1; if (r1c > M_ROWS - 1) r1c = M_ROWS - 1;
    const unsigned short* a_g1 = Xsrc + (size_t)r1c * 512 + a_k1 * 8;
    const int a_r2 = 128 + (tid >> 2);
    const int a_k2 = (tid & 3) ^ ((a_r2 >> 1) & 3);
    int r2c = r0 + a_r2; if (r2c > M_ROWS - 1) r2c = M_ROWS - 1;
    const unsigned short* a_g2 = Xsrc + (size_t)r2c * 512 + a_k2 * 8;
    // B staging: 2048 slots, 4/thread: n = u*128 + (tid>>2), kc = tid&3
    const int b_n0 = tid >> 2;
    const int b_kc = tid & 3;

    auto stage = [&](int kt) {               // stage k-chunk kt into buffer kt%3
        const int jj = kt % 3;
        const int k0 = kt * 32;
        __builtin_amdgcn_global_load_lds((const AS1 void*)(a_g1 + k0),
                                         (AS3 void*)(S3 + jj * 10240 + tid * 16), 16, 0, 0);
        if (tid < 128)
            __builtin_amdgcn_global_load_lds((const AS1 void*)(a_g2 + k0),
                                             (AS3 void*)(S3 + jj * 10240 + (512 + tid) * 16), 16, 0, 0);
#pragma unroll
        for (int u = 0; u < 4; u++) {
            int n   = u * 128 + b_n0;
            int kcs = b_kc ^ ((n >> 1) & 3);
            __builtin_amdgcn_global_load_lds((const AS1 void*)(WT + n * 512 + k0 + kcs * 8),
                                             (AS3 void*)(S3 + 30720 + jj * 32768 + (u * 512 + tid) * 16), 16, 0, 0);
        }
    };

    stage(0);
    stage(1);

    for (int it = 0; it < 16; ++it) {
        // drain only the oldest batch (6 loads for waves 0-1, 5 for waves 2-7)
        if (it < 15) {
            if (w < 2) asm volatile("s_waitcnt vmcnt(6)\n\ts_barrier" ::: "memory");
            else       asm volatile("s_waitcnt vmcnt(5)\n\ts_barrier" ::: "memory");
        } else {
            asm volatile("s_waitcnt vmcnt(0)\n\ts_barrier" ::: "memory");
        }
        if (it + 2 < 16) stage(it + 2);

        const unsigned Ab = sb + (unsigned)((it % 3) * 10240);
        const unsigned Bb = sb + 30720u + (unsigned)((it % 3) * 32768);
        short8 af[5], bf[8];
#pragma unroll
        for (int mt = 0; mt < 5; mt++) {
            int m = mg * 80 + mt * 16 + l15;
            unsigned off = Ab + (unsigned)(m * 64 + (aq ^ ((m >> 1) & 3)) * 16);
            asm volatile("ds_read_b128 %0, %1" : "=v"(af[mt]) : "v"(off));
        }
#pragma unroll
        for (int nt = 0; nt < 8; nt++) {
            int n = ng * 128 + nt * 16 + l15;
            unsigned off = Bb + (unsigned)(n * 64 + (aq ^ ((n >> 1) & 3)) * 16);
            asm volatile("ds_read_b128 %0, %1" : "=v"(bf[nt]) : "v"(off));
        }
        asm volatile("s_waitcnt lgkmcnt(0)"
                     : "+v"(af[0]), "+v"(af[1]), "+v"(af[2]), "+v"(af[3]), "+v"(af[4]),
                       "+v"(bf[0]), "+v"(bf[1]), "+v"(bf[2]), "+v"(bf[3]),
                       "+v"(bf[4]), "+v"(bf[5]), "+v"(bf[6]), "+v"(bf[7]) :: "memory");
#pragma unroll
        for (int nt = 0; nt < 8; nt++)
#pragma unroll
            for (int mt = 0; mt < 5; mt++)
                acc[mt][nt] = __builtin_amdgcn_mfma_f32_16x16x32_bf16(af[mt], bf[nt], acc[mt][nt], 0, 0, 0);
    }

    // ---- epilogue: bias + LayerNorm + fp8 store via byte LDS tile ----
    float bcol[8], gcol[8], shcol[8];
#pragma unroll
    for (int nt = 0; nt < 8; nt++) {
        int col = ng * 128 + nt * 16 + l15;
        bcol[nt]  = b2f(bia[col]);
        gcol[nt]  = b2f(gg[col]);
        shcol[nt] = b2f(sh[col]);
    }
#pragma unroll
    for (int mt = 0; mt < 5; mt++)
#pragma unroll
        for (int nt = 0; nt < 8; nt++)
#pragma unroll
            for (int r = 0; r < 4; r++) acc[mt][nt][r] += bcol[nt];

#pragma unroll
    for (int mt = 0; mt < 5; mt++)
#pragma unroll
        for (int r = 0; r < 4; r++) {
            float s = 0.f, q = 0.f;
#pragma unroll
            for (int nt = 0; nt < 8; nt++) { float x = acc[mt][nt][r]; s += x; q += x * x; }
#pragma unroll
            for (int off = 1; off < 16; off <<= 1) {
                s += __shfl_xor(s, off, 64);
                q += __shfl_xor(q, off, 64);
            }
            if (l15 == 0) {
                int row = mg * 80 + mt * 16 + aq * 4 + r;
                red[row][ng][0] = s;
                red[row][ng][1] = q;
            }
        }
    __syncthreads();   // red complete; also: all K-loop LDS reads done -> S reusable

    float mean_[5][4], rstd_[5][4];
#pragma unroll
    for (int mt = 0; mt < 5; mt++)
#pragma unroll
        for (int r = 0; r < 4; r++) {
            int row = mg * 80 + mt * 16 + aq * 4 + r;
            float s = red[row][0][0] + red[row][1][0] + red[row][2][0] + red[row][3][0];
            float q = red[row][0][1] + red[row][1][1] + red[row][2][1] + red[row][3][1];
            float mu  = s * (1.f / 512.f);
            float var = q * (1.f / 512.f) - mu * mu;
            mean_[mt][r] = mu;
            rstd_[mt][r] = rsqrtf(var + 1e-5f);
        }

    // fp8 values -> 160x528 byte tile (stride 528 = 16B-aligned), then coalesced stores
    unsigned char* ot8 = (unsigned char*)S;
#pragma unroll
    for (int mt = 0; mt < 5; mt++)
#pragma unroll
        for (int nt = 0; nt < 8; nt++)
#pragma unroll
            for (int r = 0; r < 4; r++) {
                int row = mg * 80 + mt * 16 + aq * 4 + r;
                int col = ng * 128 + nt * 16 + l15;
                float v = (acc[mt][nt][r] - mean_[mt][r]) * rstd_[mt][r] * gcol[nt] + shcol[nt];
                ot8[row * 528 + col] = f2fp8(v);
            }
    __syncthreads();

    unsigned char* obase = a12 + sel * 512;
#pragma unroll
    for (int u = 0; u < 10; u++) {
        int ci  = u * 512 + tid;             // 5120 chunks of 16 fp8
        int row = ci >> 5, cc = (ci & 31) * 16;
        int gr  = r0 + row;
        if (gr < M_ROWS) {
            uint4 vch = *(const uint4*)(ot8 + row * 528 + cc);
            *(uint4*)(obase + (size_t)gr * 1024 + cc) = vch;
        }
    }
}

// ---------------- per-edge: fp8 gather, packed-f16 Z dots, fused exp + segment sums ----
// Two edges per wave (half-wave each). Per lane: 16 fp8 elems per vector, decode
// straight to f16 (exact: e4m3 c f16), v_pk_add_f16 + v_pk_max_f16 for
// relu(a1i+a2j), v_dot2_f32_f16 against pre-converted f16 W3 (f32 accumulate).
// Max-free softmax (v in [0,~0.25] -> exp(v)/sum exact).
__global__ __launch_bounds__(256) void edge_k(
    const unsigned char* __restrict__ a12,   // fp8 rows: 1024 B/node
    const int* __restrict__ eidx,            // (B, 2, E)
    const unsigned short* __restrict__ W3h,  // f16[512]
    const unsigned short* __restrict__ W4,
    const unsigned short* __restrict__ b4p,
    float* __restrict__ Vij, float* __restrict__ Vji,
    float* __restrict__ sumI, float* __restrict__ sumJ)
{
    int gw    = (blockIdx.x * 256 + threadIdx.x) >> 6;  // wave id: 2 edges/wave
    int lane  = threadIdx.x & 63;
    int which = lane >> 5;                              // 0/1: edge within wave
    int l     = lane & 31;
    int ge    = gw * 2 + which;
    if (ge >= BE) return;
    int b   = ge / EE, e = ge - b * EE;
    int src = eidx[b * 2 * EE + e];
    int dst = eidx[b * 2 * EE + EE + e];
    const unsigned char* rs = a12 + (size_t)(b * NN + src) * 1024;
    const unsigned char* rd = a12 + (size_t)(b * NN + dst) * 1024;
    int o = l * 16;                                     // 16 fp8 elems per lane/vector
    uint4 u1s = *(const uint4*)(rs + o);
    uint4 u2s = *(const uint4*)(rs + 512 + o);
    uint4 u1d = *(const uint4*)(rd + o);
    uint4 u2d = *(const uint4*)(rd + 512 + o);
    uint4 w3a = *(const uint4*)(W3h + l * 16);          // 16 f16 = 32B
    uint4 w3b = *(const uint4*)(W3h + l * 16 + 8);

    const unsigned int U1S[4] = {u1s.x, u1s.y, u1s.z, u1s.w};
    const unsigned int U2S[4] = {u2s.x, u2s.y, u2s.z, u2s.w};
    const unsigned int U1D[4] = {u1d.x, u1d.y, u1d.z, u1d.w};
    const unsigned int U2D[4] = {u2d.x, u2d.y, u2d.z, u2d.w};
    const unsigned int W3W[8] = {w3a.x, w3a.y, w3a.z, w3a.w, w3b.x, w3b.y, w3b.z, w3b.w};
    const half2v HZ = {(_Float16)0.f, (_Float16)0.f};

    float zij = 0.f, zji = 0.f;
#define EDGE_STEP(WI, I, SEL)                                        \
    {                                                                \
        half2v wv  = uint2h2(W3W[WI]);                               \
        half2v x1s = CVT8H(U1S[I], SEL);                             \
        half2v x2s = CVT8H(U2S[I], SEL);                             \
        half2v x1d = CVT8H(U1D[I], SEL);                             \
        half2v x2d = CVT8H(U2D[I], SEL);                             \
        half2v pij = __builtin_elementwise_max(x1s + x2d, HZ);       \
        half2v pji = __builtin_elementwise_max(x1d + x2s, HZ);       \
        zij = FDOT2(pij, wv, zij);                                   \
        zji = FDOT2(pji, wv, zji);                                   \
    }
    EDGE_STEP(0, 0, false)
    EDGE_STEP(1, 0, true)
    EDGE_STEP(2, 1, false)
    EDGE_STEP(3, 1, true)
    EDGE_STEP(4, 2, false)
    EDGE_STEP(5, 2, true)
    EDGE_STEP(6, 3, false)
    EDGE_STEP(7, 3, true)
#undef EDGE_STEP

#pragma unroll
    for (int off = 16; off >= 1; off >>= 1) {           // reduce within each half-wave
        zij += __shfl_xor(zij, off, 64);
        zji += __shfl_xor(zji, off, 64);
    }
    if (l == 0) {                                       // lanes 0 and 32: one edge each
        float w4f = b2f(W4[0]);
        float b4f = b2f(b4p[0]);
        float d   = zij - zji;                          // b3 cancels exactly
        float vij = fmaf(d, w4f, b4f);  vij = vij > 0.f ? vij : 0.f;
        float vji = fmaf(-d, w4f, b4f); vji = vji > 0.f ? vji : 0.f;
        float eij = expf(vij), eji = expf(vji);
        Vij[ge] = eij;
        Vji[ge] = eji;
        atomicAdd(sumI + b * NN + src, eij);
        atomicAdd(sumJ + b * NN + dst, eji);
    }
}

// ---------------- softmax final: normalize -> bf16 or f32 out ----------------
__global__ __launch_bounds__(256) void norm_k(
    const float* __restrict__ V, const int* __restrict__ eidx,
    const float* __restrict__ sumI, const float* __restrict__ sumJ,
    const int* __restrict__ flag, void* __restrict__ out)
{
    int i = blockIdx.x * 256 + threadIdx.x;
    if (i >= 2 * BE) return;
    int seg; const float* sm;
    if (i < BE) {
        int b = i / EE, e = i - b * EE;
        seg = b * NN + eidx[b * 2 * EE + e];
        sm = sumI;
    } else {
        int j = i - BE;
        int b = j / EE, e = j - b * EE;
        seg = b * NN + eidx[b * 2 * EE + EE + e];
        sm = sumJ;
    }
    float v = V[i] / sm[seg];
    if (*flag) ((float*)out)[i] = v;
    else       ((unsigned short*)out)[i] = f2b(v);
}

extern "C" void kernel_launch(void* const* d_in, const int* in_sizes, int n_in,
                              void* d_out, int out_size, void* d_ws, size_t ws_size,
                              hipStream_t stream)
{
    (void)in_sizes; (void)n_in; (void)out_size; (void)ws_size;
    const void* X_raw = d_in[0];
    const int*  eix   = (const int*)d_in[1];
    const void* W1    = d_in[3];
    const void* b1    = d_in[4];
    const void* g1    = d_in[5];
    const void* bb1   = d_in[6];
    const void* W2    = d_in[7];
    const void* b2    = d_in[8];
    const void* g2    = d_in[9];
    const void* bb2   = d_in[10];
    const void* W3    = d_in[11];
    const void* W4    = d_in[13];
    const void* b4    = d_in[14];

    char* ws = (char*)d_ws;
    size_t off = 0;
    int* flag = (int*)(ws + off);                        off += 16;
    unsigned char*  a12 = (unsigned char*)(ws + off);    off += (size_t)M_ROWS * 1024;     // 20.48 MB fp8
    unsigned short* Xb  = (unsigned short*)(ws + off);   off += (size_t)M_PAD * 512 * 2;   // 20.6 MB
    unsigned short* T1  = (unsigned short*)(ws + off);   off += (size_t)512 * 512 * 2;
    unsigned short* T2  = (unsigned short*)(ws + off);   off += (size_t)512 * 512 * 2;
    unsigned short* P   = (unsigned short*)(ws + off);   off += 16384;                     // params + f16 W3
    float* Vbuf = (float*)(ws + off);                    off += (size_t)2 * BE * 4;
    float* Z    = (float*)(ws + off);                    off += (size_t)2 * BNN * 4;
    float* sumI = Z;
    float* sumJ = Z + BNN;

    prep_k<<<PREP_NB, 256, 0, stream>>>(X_raw, W1, W2, b1, g1, bb1, b2, g2, bb2,
                                        W3, W4, b4, flag, Xb, T1, T2, P, Z);
    gemm_ln7_k<<<dim3(126, 2), 512, 0, stream>>>((const unsigned short*)X_raw, Xb, flag,
                                                 T1, T2,
                                                 P, P + 512, P + 1024,
                                                 P + 1536, P + 2048, P + 2560, a12);
    edge_k<<<BE / 8, 256, 0, stream>>>(a12, eix, P + 3600, P + 3584, P + 3585,
                                       Vbuf, Vbuf + BE, sumI, sumJ);
    norm_k<<<(2 * BE + 255) / 256, 256, 0, stream>>>(Vbuf, eix, sumI, sumJ, flag, (unsigned short*)d_out);
}

// Round 4
// 215.442 us; speedup vs baseline: 1.1287x; 1.0098x over previous
//
#include <hip/hip_runtime.h>
#include <stdint.h>

// Problem constants (fixed by the reference setup)
#define BB 2
#define NN 10000
#define EE 100000
#define FF 512
#define HH 512
constexpr int M_ROWS = BB * NN;   // 20000 GEMM rows
constexpr int M_PAD  = 20160;     // padded to multiple of 160 (126 blocks/sel)
constexpr int BE     = BB * EE;   // 200000 edges total
constexpr int BNN    = BB * NN;   // 20000 segments

typedef __attribute__((ext_vector_type(8))) short short8;   // 8 bf16 (4 VGPRs)
typedef __attribute__((ext_vector_type(4))) float f32x4;    // MFMA accumulator
typedef __attribute__((ext_vector_type(2))) float f32x2;
typedef _Float16 half2v __attribute__((ext_vector_type(2)));

#define AS1 __attribute__((address_space(1)))
#define AS3 __attribute__((address_space(3)))

__device__ __forceinline__ float b2f(unsigned short u) {
    union { unsigned int i; float f; } v; v.i = ((unsigned int)u) << 16; return v.f;
}
__device__ __forceinline__ unsigned short f2b(float f) {   // round-to-nearest-even
    unsigned int x = __float_as_uint(f);
    x += 0x7fffu + ((x >> 16) & 1u);
    return (unsigned short)(x >> 16);
}
__device__ __forceinline__ unsigned char f2fp8(float v) {
    unsigned int p = __builtin_amdgcn_cvt_pk_fp8_f32(v, v, 0u, false);
    return (unsigned char)(p & 0xffu);
}
__device__ __forceinline__ half2v uint2h2(unsigned int u) {
    union { unsigned int u; half2v h; } v; v.u = u; return v.h;
}

// fp8(e4m3) pair -> f16 pair. sel=false: bytes[1:0], sel=true: bytes[3:2].
#if __has_builtin(__builtin_amdgcn_cvt_scalef32_pk_f16_fp8)
  #define CVT8H(u, sel) __builtin_amdgcn_cvt_scalef32_pk_f16_fp8((u), 1.0f, (sel))
#else
  #define CVT8H(u, sel) ({ f32x2 _p = __builtin_amdgcn_cvt_pk_f32_fp8((u), (sel)); \
                           (half2v){(_Float16)_p.x, (_Float16)_p.y}; })
#endif

#if __has_builtin(__builtin_amdgcn_fdot2)
  #define FDOT2(a, b, c) __builtin_amdgcn_fdot2((a), (b), (c), false)
#else
  #define FDOT2(a, b, c) ((float)(a).x * (float)(b).x + (float)(a).y * (float)(b).y + (c))
#endif

// ---------------- fused front-end: detect + convertX + transpose + params + zero ------
// One dispatch replaces five. Every block recomputes the dtype flag inline (reads
// 510 B of X, wave-0 shuffle reduce -> LDS broadcast): no cross-dispatch dependency.
// Block ranges:  [0,5000)   convertX (f32 path only; early-exit when input is bf16)
//                [5000,5512) W1/W2 transpose (32x32 tiles, 2 mats)
//                [5512,5529) param canonicalization (P layout below)
//                [5529,5686) zero segment-sum buffer
// P layout (ushort): b1@0 g1@512 bb1@1024 b2@1536 g2@2048 bb2@2560 W3(bf16)@3072
// W4@3584 b4@3585 | W3(f16)@3600..4111
constexpr int PREP_CX = 5000;
constexpr int PREP_TR = PREP_CX + 512;
constexpr int PREP_CP = PREP_TR + 17;
constexpr int PREP_NB = PREP_CP + 157;
__global__ __launch_bounds__(256) void prep_k(
    const void* __restrict__ Xraw,
    const void* __restrict__ W1, const void* __restrict__ W2,
    const void* b1, const void* g1, const void* bb1,
    const void* b2, const void* g2, const void* bb2,
    const void* W3, const void* W4, const void* b4,
    int* __restrict__ flag, unsigned short* __restrict__ Xb,
    unsigned short* __restrict__ T1, unsigned short* __restrict__ T2,
    unsigned short* __restrict__ P, float* __restrict__ Z)
{
    __shared__ int sflag;
    __shared__ unsigned short t[32][33];
    const int tid = threadIdx.x;
    const int bid = blockIdx.x;

    if (tid < 64) {                       // wave 0: dtype detect (same rule as before)
        const unsigned short* x = (const unsigned short*)Xraw;
        int good = 0;
#pragma unroll
        for (int j = 0; j < 2; j++) {
            unsigned short u = x[2 * (tid * 2 + j)];
            int e = (u >> 7) & 0xFF;
            if (e >= 100 && e <= 140) good++;
        }
#pragma unroll
        for (int off = 32; off >= 1; off >>= 1) good += __shfl_xor(good, off, 64);
        if (tid == 0) sflag = (good < 96) ? 1 : 0;
    }
    __syncthreads();
    const int isf = sflag;
    if (bid == 0 && tid == 0) *flag = isf;

    if (bid < PREP_CX) {                  // ---- convertX: only needed for f32 input
        if (!isf) return;                 // bf16 input: gemm reads X_raw directly
        int i = (bid * 256 + tid) * 8;
        if (i >= M_ROWS * 512) return;
        const float4* f = (const float4*)((const float*)Xraw + i);
        float4 a = f[0], b = f[1];
        short8 o;
        o[0] = (short)f2b(a.x); o[1] = (short)f2b(a.y);
        o[2] = (short)f2b(a.z); o[3] = (short)f2b(a.w);
        o[4] = (short)f2b(b.x); o[5] = (short)f2b(b.y);
        o[6] = (short)f2b(b.z); o[7] = (short)f2b(b.w);
        *(short8*)(Xb + i) = o;
        return;
    }
    if (bid < PREP_TR) {                  // ---- transpose W -> WT[n][k]
        int b2i = bid - PREP_CX;
        int bx = b2i & 15, by = (b2i >> 4) & 15, bz = b2i >> 8;
        const void*     W = bz ? W2 : W1;
        unsigned short* T = bz ? T2 : T1;
        int tx = tid & 31, ty = tid >> 5;   // 32 x 8
        int n0 = bx * 32, k0 = by * 32;
#pragma unroll
        for (int r = 0; r < 4; r++) {
            int k = k0 + ty + r * 8;
            unsigned short v;
            if (isf) v = f2b(((const float*)W)[k * 512 + n0 + tx]);
            else     v = ((const unsigned short*)W)[k * 512 + n0 + tx];
            t[ty + r * 8][tx] = v;
        }
        __syncthreads();
#pragma unroll
        for (int r = 0; r < 4; r++) {
            int n = n0 + ty + r * 8;
            T[n * 512 + k0 + tx] = t[tx][ty + r * 8];
        }
        return;
    }
    if (bid < PREP_CP) {                  // ---- small params
        int i = (bid - PREP_TR) * 256 + tid;
        if (i >= 4098) return;
        if (i >= 3586) {                  // W3 -> f16 copy for edge_k dot2
            int j = i - 3586;             // 0..511
            float f;
            if (isf) f = ((const float*)W3)[j];
            else     f = b2f(((const unsigned short*)W3)[j]);
            union { _Float16 h; unsigned short u; } cv;
            cv.h = (_Float16)f;
            P[3600 + j] = cv.u;
            return;
        }
        const void* src; int off;
        if      (i < 512)  { src = b1;  off = i; }
        else if (i < 1024) { src = g1;  off = i - 512; }
        else if (i < 1536) { src = bb1; off = i - 1024; }
        else if (i < 2048) { src = b2;  off = i - 1536; }
        else if (i < 2560) { src = g2;  off = i - 2048; }
        else if (i < 3072) { src = bb2; off = i - 2560; }
        else if (i < 3584) { src = W3;  off = i - 3072; }
        else if (i == 3584){ src = W4;  off = 0; }
        else               { src = b4;  off = 0; }
        unsigned short v;
        if (isf) v = f2b(((const float*)src)[off]);
        else     v = ((const unsigned short*)src)[off];
        P[i] = v;
        return;
    }
    {                                     // ---- zero segment sums
        int i = (bid - PREP_CP) * 256 + tid;
        if (i < 2 * BNN) Z[i] = 0.f;
    }
}

// ---------------- fused GEMM (X @ W) + bias + LayerNorm -> a12 (fp8 e4m3) ----------------
// v9 structure (v7 restored): BM=160, grid 126x2 = 252 blocks <= 256 CUs: ONE round.
// Triple-buffered LDS (A 3x10KB, B 3x32KB), depth-2 prefetch, per-iter counted drain
// vmcnt(6)/vmcnt(5). A-source is flag-selected (bf16 input -> X_raw zero-copy; f32 ->
// canonical Xb), A-row clamp to M_ROWS-1 for the pad tile.
// Known profile (R3): 64.0 us, FETCH 56 MB, MfmaUtil 12%. Iteration-cost model:
// ~3.3 us fixed convoy + bytes/15TB/s per iter; next lever is BK=64 (8 iters) but it
// needs A-in-regs to fit LDS -- deferred, kernel untouched this round.
__global__ __launch_bounds__(512, 2) void gemm_ln7_k(
    const unsigned short* __restrict__ Xraw,  // raw input viewed as ushort (bf16 path)
    const unsigned short* __restrict__ Xb,    // canonical bf16 (f32 path)
    const int* __restrict__ flagp,
    const unsigned short* __restrict__ WT1,   // 512(n) x 512(k)  (pre-transposed bf16)
    const unsigned short* __restrict__ WT2,
    const unsigned short* __restrict__ bia1, const unsigned short* __restrict__ gg1, const unsigned short* __restrict__ sh1,
    const unsigned short* __restrict__ bia2, const unsigned short* __restrict__ gg2, const unsigned short* __restrict__ sh2,
    unsigned char* __restrict__ a12)          // 20000 x 1024 fp8 (a1 | a2)
{
    __shared__ __align__(16) unsigned short S[64512];  // 126 KB: A 3x10240B @0, B 3x32768B @30720; epilogue reuses as 160x528 byte tile
    __shared__ float red[160][4][2];

    const int sel = blockIdx.y;
    const unsigned short* WT  = sel ? WT2 : WT1;
    const unsigned short* bia = sel ? bia2 : bia1;
    const unsigned short* gg  = sel ? gg2 : gg1;
    const unsigned short* sh  = sel ? sh2 : sh1;
    const int r0   = blockIdx.x * 160;
    const int tid  = threadIdx.x;
    const int lane = tid & 63;
    const int w    = tid >> 6;      // 0..7
    const int mg   = w >> 2;        // 0..1  (80-row group)
    const int ng   = w & 3;         // 0..3  (128-col group)
    const int aq   = lane >> 4;     // 0..3
    const int l15  = lane & 15;

    const unsigned short* Xsrc = (*flagp) ? Xb : Xraw;

    AS3 char* S3 = (AS3 char*)S;
    const unsigned sb = (unsigned)(unsigned long long)S3;

    f32x4 acc[5][8];
#pragma unroll
    for (int i = 0; i < 5; i++)
#pragma unroll
        for (int j = 0; j < 8; j++) acc[i][j] = (f32x4){0.f, 0.f, 0.f, 0.f};

    // A staging: 640 slots (16B each). slot sid: r = sid>>2, kc = sid&3 (XOR-swizzled).
    // threads 0..511 take sid = tid; threads 0..127 (waves 0-1) also take sid = 512+tid.
    // Global row clamped to M_ROWS-1 (pad rows duplicate row 19999; stores masked).
    const int a_r1 = tid >> 2;
    const int a_k1 = (tid & 3) ^ ((a_r1 >> 1) & 3);
    int r1c = r0 + a_r1; if (r1c > M_ROWS - 1) r1c = M_ROWS - 1;
    const unsigned short* a_g1 = Xsrc + (size_t)r1c * 512 + a_k1 * 8;
    const int a_r2 = 128 + (tid >> 2);
    const int a_k2 = (tid & 3) ^ ((a_r2 >> 1) & 3);
    int r2c = r0 + a_r2; if (r2c > M_ROWS - 1) r2c = M_ROWS - 1;
    const unsigned short* a_g2 = Xsrc + (size_t)r2c * 512 + a_k2 * 8;
    // B staging: 2048 slots, 4/thread: n = u*128 + (tid>>2), kc = tid&3
    const int b_n0 = tid >> 2;
    const int b_kc = tid & 3;

    auto stage = [&](int kt) {               // stage k-chunk kt into buffer kt%3
        const int jj = kt % 3;
        const int k0 = kt * 32;
        __builtin_amdgcn_global_load_lds((const AS1 void*)(a_g1 + k0),
                                         (AS3 void*)(S3 + jj * 10240 + tid * 16), 16, 0, 0);
        if (tid < 128)
            __builtin_amdgcn_global_load_lds((const AS1 void*)(a_g2 + k0),
                                             (AS3 void*)(S3 + jj * 10240 + (512 + tid) * 16), 16, 0, 0);
#pragma unroll
        for (int u = 0; u < 4; u++) {
            int n   = u * 128 + b_n0;
            int kcs = b_kc ^ ((n >> 1) & 3);
            __builtin_amdgcn_global_load_lds((const AS1 void*)(WT + n * 512 + k0 + kcs * 8),
                                             (AS3 void*)(S3 + 30720 + jj * 32768 + (u * 512 + tid) * 16), 16, 0, 0);
        }
    };

    stage(0);
    stage(1);

    for (int it = 0; it < 16; ++it) {
        // drain only the oldest batch (6 loads for waves 0-1, 5 for waves 2-7)
        if (it < 15) {
            if (w < 2) asm volatile("s_waitcnt vmcnt(6)\n\ts_barrier" ::: "memory");
            else       asm volatile("s_waitcnt vmcnt(5)\n\ts_barrier" ::: "memory");
        } else {
            asm volatile("s_waitcnt vmcnt(0)\n\ts_barrier" ::: "memory");
        }
        if (it + 2 < 16) stage(it + 2);

        const unsigned Ab = sb + (unsigned)((it % 3) * 10240);
        const unsigned Bb = sb + 30720u + (unsigned)((it % 3) * 32768);
        short8 af[5], bf[8];
#pragma unroll
        for (int mt = 0; mt < 5; mt++) {
            int m = mg * 80 + mt * 16 + l15;
            unsigned off = Ab + (unsigned)(m * 64 + (aq ^ ((m >> 1) & 3)) * 16);
            asm volatile("ds_read_b128 %0, %1" : "=v"(af[mt]) : "v"(off));
        }
#pragma unroll
        for (int nt = 0; nt < 8; nt++) {
            int n = ng * 128 + nt * 16 + l15;
            unsigned off = Bb + (unsigned)(n * 64 + (aq ^ ((n >> 1) & 3)) * 16);
            asm volatile("ds_read_b128 %0, %1" : "=v"(bf[nt]) : "v"(off));
        }
        asm volatile("s_waitcnt lgkmcnt(0)"
                     : "+v"(af[0]), "+v"(af[1]), "+v"(af[2]), "+v"(af[3]), "+v"(af[4]),
                       "+v"(bf[0]), "+v"(bf[1]), "+v"(bf[2]), "+v"(bf[3]),
                       "+v"(bf[4]), "+v"(bf[5]), "+v"(bf[6]), "+v"(bf[7]) :: "memory");
#pragma unroll
        for (int nt = 0; nt < 8; nt++)
#pragma unroll
            for (int mt = 0; mt < 5; mt++)
                acc[mt][nt] = __builtin_amdgcn_mfma_f32_16x16x32_bf16(af[mt], bf[nt], acc[mt][nt], 0, 0, 0);
    }

    // ---- epilogue: bias + LayerNorm + fp8 store via byte LDS tile ----
    float bcol[8], gcol[8], shcol[8];
#pragma unroll
    for (int nt = 0; nt < 8; nt++) {
        int col = ng * 128 + nt * 16 + l15;
        bcol[nt]  = b2f(bia[col]);
        gcol[nt]  = b2f(gg[col]);
        shcol[nt] = b2f(sh[col]);
    }
#pragma unroll
    for (int mt = 0; mt < 5; mt++)
#pragma unroll
        for (int nt = 0; nt < 8; nt++)
#pragma unroll
            for (int r = 0; r < 4; r++) acc[mt][nt][r] += bcol[nt];

#pragma unroll
    for (int mt = 0; mt < 5; mt++)
#pragma unroll
        for (int r = 0; r < 4; r++) {
            float s = 0.f, q = 0.f;
#pragma unroll
            for (int nt = 0; nt < 8; nt++) { float x = acc[mt][nt][r]; s += x; q += x * x; }
#pragma unroll
            for (int off = 1; off < 16; off <<= 1) {
                s += __shfl_xor(s, off, 64);
                q += __shfl_xor(q, off, 64);
            }
            if (l15 == 0) {
                int row = mg * 80 + mt * 16 + aq * 4 + r;
                red[row][ng][0] = s;
                red[row][ng][1] = q;
            }
        }
    __syncthreads();   // red complete; also: all K-loop LDS reads done -> S reusable

    float mean_[5][4], rstd_[5][4];
#pragma unroll
    for (int mt = 0; mt < 5; mt++)
#pragma unroll
        for (int r = 0; r < 4; r++) {
            int row = mg * 80 + mt * 16 + aq * 4 + r;
            float s = red[row][0][0] + red[row][1][0] + red[row][2][0] + red[row][3][0];
            float q = red[row][0][1] + red[row][1][1] + red[row][2][1] + red[row][3][1];
            float mu  = s * (1.f / 512.f);
            float var = q * (1.f / 512.f) - mu * mu;
            mean_[mt][r] = mu;
            rstd_[mt][r] = rsqrtf(var + 1e-5f);
        }

    // fp8 values -> 160x528 byte tile (stride 528 = 16B-aligned), then coalesced stores
    unsigned char* ot8 = (unsigned char*)S;
#pragma unroll
    for (int mt = 0; mt < 5; mt++)
#pragma unroll
        for (int nt = 0; nt < 8; nt++)
#pragma unroll
            for (int r = 0; r < 4; r++) {
                int row = mg * 80 + mt * 16 + aq * 4 + r;
                int col = ng * 128 + nt * 16 + l15;
                float v = (acc[mt][nt][r] - mean_[mt][r]) * rstd_[mt][r] * gcol[nt] + shcol[nt];
                ot8[row * 528 + col] = f2fp8(v);
            }
    __syncthreads();

    unsigned char* obase = a12 + sel * 512;
#pragma unroll
    for (int u = 0; u < 10; u++) {
        int ci  = u * 512 + tid;             // 5120 chunks of 16 fp8
        int row = ci >> 5, cc = (ci & 31) * 16;
        int gr  = r0 + row;
        if (gr < M_ROWS) {
            uint4 vch = *(const uint4*)(ot8 + row * 528 + cc);
            *(uint4*)(obase + (size_t)gr * 1024 + cc) = vch;
        }
    }
}

// ---------------- per-edge: fp8 gather, packed-f16 Z dots, fused exp + segment sums ----
// v3: FOUR edges per wave (2 per half-wave, computed back-to-back). All 8 row-gathers
// are issued before any compute -> 2x memory-level parallelism per wave vs v2; the
// index loads and W3 registers are amortized over 2x edges; paired output stores
// (float2). Rationale: v2 sat at ~48 us, between its VALU floor (~10 us) and fetch
// floor (~24 us) -> gather-latency-bound; deeper MLP attacks exactly that.
// Max-free softmax (v in [0,~0.25] -> exp(v)/sum exact).
__global__ __launch_bounds__(256) void edge_k(
    const unsigned char* __restrict__ a12,   // fp8 rows: 1024 B/node
    const int* __restrict__ eidx,            // (B, 2, E)
    const unsigned short* __restrict__ W3h,  // f16[512]
    const unsigned short* __restrict__ W4,
    const unsigned short* __restrict__ b4p,
    float* __restrict__ Vij, float* __restrict__ Vji,
    float* __restrict__ sumI, float* __restrict__ sumJ)
{
    int wid   = (blockIdx.x * 256 + threadIdx.x) >> 6;  // wave id: 4 edges/wave
    int lane  = threadIdx.x & 63;
    int which = lane >> 5;                              // 0/1: edge-pair within wave
    int l     = lane & 31;
    int e0    = wid * 4 + which * 2;                    // this half-wave: edges e0, e0+1
    // grid is exact (BE/4 waves); e0, e0+1 never straddle the batch boundary (EE even)
    int b  = e0 / EE, ei = e0 - b * EE;
    const int* ebase = eidx + b * 2 * EE;
    int srcA = ebase[ei],      srcB = ebase[ei + 1];
    int dstA = ebase[EE + ei], dstB = ebase[EE + ei + 1];
    const unsigned char* nb = a12 + (size_t)(b * NN) * 1024;
    const unsigned char* rsA = nb + (size_t)srcA * 1024;
    const unsigned char* rdA = nb + (size_t)dstA * 1024;
    const unsigned char* rsB = nb + (size_t)srcB * 1024;
    const unsigned char* rdB = nb + (size_t)dstB * 1024;
    int o = l * 16;                                     // 16 fp8 elems per lane/vector

    // issue all 8 gathers (4/edge x 2 edges) up front: 2x MLP
    uint4 u1sA = *(const uint4*)(rsA + o);
    uint4 u2sA = *(const uint4*)(rsA + 512 + o);
    uint4 u1dA = *(const uint4*)(rdA + o);
    uint4 u2dA = *(const uint4*)(rdA + 512 + o);
    uint4 u1sB = *(const uint4*)(rsB + o);
    uint4 u2sB = *(const uint4*)(rsB + 512 + o);
    uint4 u1dB = *(const uint4*)(rdB + o);
    uint4 u2dB = *(const uint4*)(rdB + 512 + o);
    uint4 w3a = *(const uint4*)(W3h + l * 16);          // 16 f16 = 32B
    uint4 w3b = *(const uint4*)(W3h + l * 16 + 8);

    const unsigned int W3W[8] = {w3a.x, w3a.y, w3a.z, w3a.w, w3b.x, w3b.y, w3b.z, w3b.w};
    const half2v HZ = {(_Float16)0.f, (_Float16)0.f};

    float zijA = 0.f, zjiA = 0.f, zijB = 0.f, zjiB = 0.f;
#define EDGE_STEP(ZI, ZJ, V1S, V2S, V1D, V2D, WI, C, SEL)            \
    {                                                                \
        half2v wv  = uint2h2(W3W[WI]);                               \
        half2v x1s = CVT8H(V1S.C, SEL);                              \
        half2v x2s = CVT8H(V2S.C, SEL);                              \
        half2v x1d = CVT8H(V1D.C, SEL);                              \
        half2v x2d = CVT8H(V2D.C, SEL);                              \
        half2v pij = __builtin_elementwise_max(x1s + x2d, HZ);       \
        half2v pji = __builtin_elementwise_max(x1d + x2s, HZ);       \
        ZI = FDOT2(pij, wv, ZI);                                     \
        ZJ = FDOT2(pji, wv, ZJ);                                     \
    }
#define EDGE_ALL(ZI, ZJ, V1S, V2S, V1D, V2D)                         \
    EDGE_STEP(ZI, ZJ, V1S, V2S, V1D, V2D, 0, x, false)               \
    EDGE_STEP(ZI, ZJ, V1S, V2S, V1D, V2D, 1, x, true)                \
    EDGE_STEP(ZI, ZJ, V1S, V2S, V1D, V2D, 2, y, false)               \
    EDGE_STEP(ZI, ZJ, V1S, V2S, V1D, V2D, 3, y, true)                \
    EDGE_STEP(ZI, ZJ, V1S, V2S, V1D, V2D, 4, z, false)               \
    EDGE_STEP(ZI, ZJ, V1S, V2S, V1D, V2D, 5, z, true)                \
    EDGE_STEP(ZI, ZJ, V1S, V2S, V1D, V2D, 6, w, false)               \
    EDGE_STEP(ZI, ZJ, V1S, V2S, V1D, V2D, 7, w, true)

    EDGE_ALL(zijA, zjiA, u1sA, u2sA, u1dA, u2dA)
    EDGE_ALL(zijB, zjiB, u1sB, u2sB, u1dB, u2dB)
#undef EDGE_ALL
#undef EDGE_STEP

#pragma unroll
    for (int off = 16; off >= 1; off >>= 1) {           // reduce within each half-wave
        zijA += __shfl_xor(zijA, off, 64);
        zjiA += __shfl_xor(zjiA, off, 64);
        zijB += __shfl_xor(zijB, off, 64);
        zjiB += __shfl_xor(zjiB, off, 64);
    }
    if (l == 0) {                                       // lanes 0 and 32: one pair each
        float w4f = b2f(W4[0]);
        float b4f = b2f(b4p[0]);
        float dA   = zijA - zjiA;                       // b3 cancels exactly
        float vijA = fmaf(dA, w4f, b4f);  vijA = vijA > 0.f ? vijA : 0.f;
        float vjiA = fmaf(-dA, w4f, b4f); vjiA = vjiA > 0.f ? vjiA : 0.f;
        float dB   = zijB - zjiB;
        float vijB = fmaf(dB, w4f, b4f);  vijB = vijB > 0.f ? vijB : 0.f;
        float vjiB = fmaf(-dB, w4f, b4f); vjiB = vjiB > 0.f ? vjiB : 0.f;
        float eijA = expf(vijA), ejiA = expf(vjiA);
        float eijB = expf(vijB), ejiB = expf(vjiB);
        *(float2*)(Vij + e0) = (float2){eijA, eijB};    // e0 even -> aligned
        *(float2*)(Vji + e0) = (float2){ejiA, ejiB};
        atomicAdd(sumI + b * NN + srcA, eijA);
        atomicAdd(sumJ + b * NN + dstA, ejiA);
        atomicAdd(sumI + b * NN + srcB, eijB);
        atomicAdd(sumJ + b * NN + dstB, ejiB);
    }
}

// ---------------- softmax final: normalize -> bf16 or f32 out ----------------
__global__ __launch_bounds__(256) void norm_k(
    const float* __restrict__ V, const int* __restrict__ eidx,
    const float* __restrict__ sumI, const float* __restrict__ sumJ,
    const int* __restrict__ flag, void* __restrict__ out)
{
    int i = blockIdx.x * 256 + threadIdx.x;
    if (i >= 2 * BE) return;
    int seg; const float* sm;
    if (i < BE) {
        int b = i / EE, e = i - b * EE;
        seg = b * NN + eidx[b * 2 * EE + e];
        sm = sumI;
    } else {
        int j = i - BE;
        int b = j / EE, e = j - b * EE;
        seg = b * NN + eidx[b * 2 * EE + EE + e];
        sm = sumJ;
    }
    float v = V[i] / sm[seg];
    if (*flag) ((float*)out)[i] = v;
    else       ((unsigned short*)out)[i] = f2b(v);
}

extern "C" void kernel_launch(void* const* d_in, const int* in_sizes, int n_in,
                              void* d_out, int out_size, void* d_ws, size_t ws_size,
                              hipStream_t stream)
{
    (void)in_sizes; (void)n_in; (void)out_size; (void)ws_size;
    const void* X_raw = d_in[0];
    const int*  eix   = (const int*)d_in[1];
    const void* W1    = d_in[3];
    const void* b1    = d_in[4];
    const void* g1    = d_in[5];
    const void* bb1   = d_in[6];
    const void* W2    = d_in[7];
    const void* b2    = d_in[8];
    const void* g2    = d_in[9];
    const void* bb2   = d_in[10];
    const void* W3    = d_in[11];
    const void* W4    = d_in[13];
    const void* b4    = d_in[14];

    char* ws = (char*)d_ws;
    size_t off = 0;
    int* flag = (int*)(ws + off);                        off += 16;
    unsigned char*  a12 = (unsigned char*)(ws + off);    off += (size_t)M_ROWS * 1024;     // 20.48 MB fp8
    unsigned short* Xb  = (unsigned short*)(ws + off);   off += (size_t)M_PAD * 512 * 2;   // 20.6 MB
    unsigned short* T1  = (unsigned short*)(ws + off);   off += (size_t)512 * 512 * 2;
    unsigned short* T2  = (unsigned short*)(ws + off);   off += (size_t)512 * 512 * 2;
    unsigned short* P   = (unsigned short*)(ws + off);   off += 16384;                     // params + f16 W3
    float* Vbuf = (float*)(ws + off);                    off += (size_t)2 * BE * 4;
    float* Z    = (float*)(ws + off);                    off += (size_t)2 * BNN * 4;
    float* sumI = Z;
    float* sumJ = Z + BNN;

    prep_k<<<PREP_NB, 256, 0, stream>>>(X_raw, W1, W2, b1, g1, bb1, b2, g2, bb2,
                                        W3, W4, b4, flag, Xb, T1, T2, P, Z);
    gemm_ln7_k<<<dim3(126, 2), 512, 0, stream>>>((const unsigned short*)X_raw, Xb, flag,
                                                 T1, T2,
                                                 P, P + 512, P + 1024,
                                                 P + 1536, P + 2048, P + 2560, a12);
    edge_k<<<BE / 16, 256, 0, stream>>>(a12, eix, P + 3600, P + 3584, P + 3585,
                                        Vbuf, Vbuf + BE, sumI, sumJ);
    norm_k<<<(2 * BE + 255) / 256, 256, 0, stream>>>(Vbuf, eix, sumI, sumJ, flag, (unsigned short*)d_out);
}

// Round 5
// 211.915 us; speedup vs baseline: 1.1474x; 1.0166x over previous
//
#include <hip/hip_runtime.h>
#include <stdint.h>

// Problem constants (fixed by the reference setup)
#define BB 2
#define NN 10000
#define EE 100000
#define FF 512
#define HH 512
constexpr int M_ROWS = BB * NN;   // 20000 GEMM rows
constexpr int M_PAD  = 20160;     // padded to multiple of 160 (126 blocks/sel)
constexpr int BE     = BB * EE;   // 200000 edges total
constexpr int BNN    = BB * NN;   // 20000 segments

typedef __attribute__((ext_vector_type(8))) short short8;   // 8 bf16 (4 VGPRs)
typedef __attribute__((ext_vector_type(4))) float f32x4;    // MFMA accumulator
typedef __attribute__((ext_vector_type(2))) float f32x2;
typedef _Float16 half2v __attribute__((ext_vector_type(2)));

#define AS1 __attribute__((address_space(1)))
#define AS3 __attribute__((address_space(3)))

__device__ __forceinline__ float b2f(unsigned short u) {
    union { unsigned int i; float f; } v; v.i = ((unsigned int)u) << 16; return v.f;
}
__device__ __forceinline__ unsigned short f2b(float f) {   // round-to-nearest-even
    unsigned int x = __float_as_uint(f);
    x += 0x7fffu + ((x >> 16) & 1u);
    return (unsigned short)(x >> 16);
}
__device__ __forceinline__ unsigned char f2fp8(float v) {
    unsigned int p = __builtin_amdgcn_cvt_pk_fp8_f32(v, v, 0u, false);
    return (unsigned char)(p & 0xffu);
}
__device__ __forceinline__ half2v uint2h2(unsigned int u) {
    union { unsigned int u; half2v h; } v; v.u = u; return v.h;
}

// fp8(e4m3) pair -> f16 pair. sel=false: bytes[1:0], sel=true: bytes[3:2].
#if __has_builtin(__builtin_amdgcn_cvt_scalef32_pk_f16_fp8)
  #define CVT8H(u, sel) __builtin_amdgcn_cvt_scalef32_pk_f16_fp8((u), 1.0f, (sel))
#else
  #define CVT8H(u, sel) ({ f32x2 _p = __builtin_amdgcn_cvt_pk_f32_fp8((u), (sel)); \
                           (half2v){(_Float16)_p.x, (_Float16)_p.y}; })
#endif

#if __has_builtin(__builtin_amdgcn_fdot2)
  #define FDOT2(a, b, c) __builtin_amdgcn_fdot2((a), (b), (c), false)
#else
  #define FDOT2(a, b, c) ((float)(a).x * (float)(b).x + (float)(a).y * (float)(b).y + (c))
#endif

// ---------------- fused front-end: detect + convertX + transpose + params + zero ------
// One dispatch replaces five. Every block recomputes the dtype flag inline (reads
// 510 B of X, wave-0 shuffle reduce -> LDS broadcast): no cross-dispatch dependency.
// Block ranges:  [0,5000)   convertX (f32 path only; early-exit when input is bf16)
//                [5000,5512) W1/W2 transpose (32x32 tiles, 2 mats)
//                [5512,5529) param canonicalization (P layout below)
//                [5529,5686) zero segment-sum buffer
// P layout (ushort): b1@0 g1@512 bb1@1024 b2@1536 g2@2048 bb2@2560 W3(bf16)@3072
// W4@3584 b4@3585 | W3(f16)@3600..4111
constexpr int PREP_CX = 5000;
constexpr int PREP_TR = PREP_CX + 512;
constexpr int PREP_CP = PREP_TR + 17;
constexpr int PREP_NB = PREP_CP + 157;
__global__ __launch_bounds__(256) void prep_k(
    const void* __restrict__ Xraw,
    const void* __restrict__ W1, const void* __restrict__ W2,
    const void* b1, const void* g1, const void* bb1,
    const void* b2, const void* g2, const void* bb2,
    const void* W3, const void* W4, const void* b4,
    int* __restrict__ flag, unsigned short* __restrict__ Xb,
    unsigned short* __restrict__ T1, unsigned short* __restrict__ T2,
    unsigned short* __restrict__ P, float* __restrict__ Z)
{
    __shared__ int sflag;
    __shared__ unsigned short t[32][33];
    const int tid = threadIdx.x;
    const int bid = blockIdx.x;

    if (tid < 64) {                       // wave 0: dtype detect (same rule as before)
        const unsigned short* x = (const unsigned short*)Xraw;
        int good = 0;
#pragma unroll
        for (int j = 0; j < 2; j++) {
            unsigned short u = x[2 * (tid * 2 + j)];
            int e = (u >> 7) & 0xFF;
            if (e >= 100 && e <= 140) good++;
        }
#pragma unroll
        for (int off = 32; off >= 1; off >>= 1) good += __shfl_xor(good, off, 64);
        if (tid == 0) sflag = (good < 96) ? 1 : 0;
    }
    __syncthreads();
    const int isf = sflag;
    if (bid == 0 && tid == 0) *flag = isf;

    if (bid < PREP_CX) {                  // ---- convertX: only needed for f32 input
        if (!isf) return;                 // bf16 input: gemm reads X_raw directly
        int i = (bid * 256 + tid) * 8;
        if (i >= M_ROWS * 512) return;
        const float4* f = (const float4*)((const float*)Xraw + i);
        float4 a = f[0], b = f[1];
        short8 o;
        o[0] = (short)f2b(a.x); o[1] = (short)f2b(a.y);
        o[2] = (short)f2b(a.z); o[3] = (short)f2b(a.w);
        o[4] = (short)f2b(b.x); o[5] = (short)f2b(b.y);
        o[6] = (short)f2b(b.z); o[7] = (short)f2b(b.w);
        *(short8*)(Xb + i) = o;
        return;
    }
    if (bid < PREP_TR) {                  // ---- transpose W -> WT[n][k]
        int b2i = bid - PREP_CX;
        int bx = b2i & 15, by = (b2i >> 4) & 15, bz = b2i >> 8;
        const void*     W = bz ? W2 : W1;
        unsigned short* T = bz ? T2 : T1;
        int tx = tid & 31, ty = tid >> 5;   // 32 x 8
        int n0 = bx * 32, k0 = by * 32;
#pragma unroll
        for (int r = 0; r < 4; r++) {
            int k = k0 + ty + r * 8;
            unsigned short v;
            if (isf) v = f2b(((const float*)W)[k * 512 + n0 + tx]);
            else     v = ((const unsigned short*)W)[k * 512 + n0 + tx];
            t[ty + r * 8][tx] = v;
        }
        __syncthreads();
#pragma unroll
        for (int r = 0; r < 4; r++) {
            int n = n0 + ty + r * 8;
            T[n * 512 + k0 + tx] = t[tx][ty + r * 8];
        }
        return;
    }
    if (bid < PREP_CP) {                  // ---- small params
        int i = (bid - PREP_TR) * 256 + tid;
        if (i >= 4098) return;
        if (i >= 3586) {                  // W3 -> f16 copy for edge_k dot2
            int j = i - 3586;             // 0..511
            float f;
            if (isf) f = ((const float*)W3)[j];
            else     f = b2f(((const unsigned short*)W3)[j]);
            union { _Float16 h; unsigned short u; } cv;
            cv.h = (_Float16)f;
            P[3600 + j] = cv.u;
            return;
        }
        const void* src; int off;
        if      (i < 512)  { src = b1;  off = i; }
        else if (i < 1024) { src = g1;  off = i - 512; }
        else if (i < 1536) { src = bb1; off = i - 1024; }
        else if (i < 2048) { src = b2;  off = i - 1536; }
        else if (i < 2560) { src = g2;  off = i - 2048; }
        else if (i < 3072) { src = bb2; off = i - 2560; }
        else if (i < 3584) { src = W3;  off = i - 3072; }
        else if (i == 3584){ src = W4;  off = 0; }
        else               { src = b4;  off = 0; }
        unsigned short v;
        if (isf) v = f2b(((const float*)src)[off]);
        else     v = ((const unsigned short*)src)[off];
        P[i] = v;
        return;
    }
    {                                     // ---- zero segment sums
        int i = (bid - PREP_CP) * 256 + tid;
        if (i < 2 * BNN) Z[i] = 0.f;
    }
}

// ---------------- fused GEMM (X @ W) + bias + LayerNorm -> a12 (fp8 e4m3) ----------------
// v10 = v9 + K-STAGGER. Theory: all 252 blocks ran barrier-locked in lockstep, every
// iteration fetching the SAME 32KB B-chunk of WT -> ~32 CUs/XCD hammering identical L2
// lines in the same window (same-address L2 convoy); that's the only mechanism found
// that explains ~4us/iter against ~0.2us of on-CU work (MFMA 400cyc, LDS ~1100cyc,
// HBM 875 GB/s all far from limits). Fix: block with linear id lin starts its K loop
// at chunk kstart=(lin>>3)&15 and wraps (kc=(kstart+it)&15). Within an XCD (lin = xcd
// mod 8) consecutive blocks get consecutive kstart -> each B-chunk served to ~2 CUs
// per XCD at a time instead of ~32. FP effect: K-summation order changes (reorder
// noise << fp8 quantization). Buffer rotation keys off the loop counter (t%3);
// staging/drain schedule (vmcnt(6)/(5), depth-2 prefetch) untouched.
__global__ __launch_bounds__(512, 2) void gemm_ln7_k(
    const unsigned short* __restrict__ Xraw,  // raw input viewed as ushort (bf16 path)
    const unsigned short* __restrict__ Xb,    // canonical bf16 (f32 path)
    const int* __restrict__ flagp,
    const unsigned short* __restrict__ WT1,   // 512(n) x 512(k)  (pre-transposed bf16)
    const unsigned short* __restrict__ WT2,
    const unsigned short* __restrict__ bia1, const unsigned short* __restrict__ gg1, const unsigned short* __restrict__ sh1,
    const unsigned short* __restrict__ bia2, const unsigned short* __restrict__ gg2, const unsigned short* __restrict__ sh2,
    unsigned char* __restrict__ a12)          // 20000 x 1024 fp8 (a1 | a2)
{
    __shared__ __align__(16) unsigned short S[64512];  // 126 KB: A 3x10240B @0, B 3x32768B @30720; epilogue reuses as 160x528 byte tile
    __shared__ float red[160][4][2];

    const int sel = blockIdx.y;
    const unsigned short* WT  = sel ? WT2 : WT1;
    const unsigned short* bia = sel ? bia2 : bia1;
    const unsigned short* gg  = sel ? gg2 : gg1;
    const unsigned short* sh  = sel ? sh2 : sh1;
    const int r0   = blockIdx.x * 160;
    const int tid  = threadIdx.x;
    const int lane = tid & 63;
    const int w    = tid >> 6;      // 0..7
    const int mg   = w >> 2;        // 0..1  (80-row group)
    const int ng   = w & 3;         // 0..3  (128-col group)
    const int aq   = lane >> 4;     // 0..3
    const int l15  = lane & 15;

    // K-stagger: blocks co-resident on one XCD (same lin mod 8) get consecutive
    // start chunks -> B-chunk requests are spread over the whole 512KB WT.
    const int lin    = blockIdx.x + 126 * sel;
    const int kstart = (lin >> 3) & 15;

    const unsigned short* Xsrc = (*flagp) ? Xb : Xraw;

    AS3 char* S3 = (AS3 char*)S;
    const unsigned sb = (unsigned)(unsigned long long)S3;

    f32x4 acc[5][8];
#pragma unroll
    for (int i = 0; i < 5; i++)
#pragma unroll
        for (int j = 0; j < 8; j++) acc[i][j] = (f32x4){0.f, 0.f, 0.f, 0.f};

    // A staging: 640 slots (16B each). slot sid: r = sid>>2, kc = sid&3 (XOR-swizzled).
    // threads 0..511 take sid = tid; threads 0..127 (waves 0-1) also take sid = 512+tid.
    // Global row clamped to M_ROWS-1 (pad rows duplicate row 19999; stores masked).
    const int a_r1 = tid >> 2;
    const int a_k1 = (tid & 3) ^ ((a_r1 >> 1) & 3);
    int r1c = r0 + a_r1; if (r1c > M_ROWS - 1) r1c = M_ROWS - 1;
    const unsigned short* a_g1 = Xsrc + (size_t)r1c * 512 + a_k1 * 8;
    const int a_r2 = 128 + (tid >> 2);
    const int a_k2 = (tid & 3) ^ ((a_r2 >> 1) & 3);
    int r2c = r0 + a_r2; if (r2c > M_ROWS - 1) r2c = M_ROWS - 1;
    const unsigned short* a_g2 = Xsrc + (size_t)r2c * 512 + a_k2 * 8;
    // B staging: 2048 slots, 4/thread: n = u*128 + (tid>>2), kc = tid&3
    const int b_n0 = tid >> 2;
    const int b_kc = tid & 3;

    auto stage = [&](int t) {                // stage logical step t: chunk (kstart+t)&15 -> buffer t%3
        const int jj = t % 3;
        const int k0 = ((kstart + t) & 15) * 32;
        __builtin_amdgcn_global_load_lds((const AS1 void*)(a_g1 + k0),
                                         (AS3 void*)(S3 + jj * 10240 + tid * 16), 16, 0, 0);
        if (tid < 128)
            __builtin_amdgcn_global_load_lds((const AS1 void*)(a_g2 + k0),
                                             (AS3 void*)(S3 + jj * 10240 + (512 + tid) * 16), 16, 0, 0);
#pragma unroll
        for (int u = 0; u < 4; u++) {
            int n   = u * 128 + b_n0;
            int kcs = b_kc ^ ((n >> 1) & 3);
            __builtin_amdgcn_global_load_lds((const AS1 void*)(WT + n * 512 + k0 + kcs * 8),
                                             (AS3 void*)(S3 + 30720 + jj * 32768 + (u * 512 + tid) * 16), 16, 0, 0);
        }
    };

    stage(0);
    stage(1);

    for (int it = 0; it < 16; ++it) {
        // drain only the oldest batch (6 loads for waves 0-1, 5 for waves 2-7)
        if (it < 15) {
            if (w < 2) asm volatile("s_waitcnt vmcnt(6)\n\ts_barrier" ::: "memory");
            else       asm volatile("s_waitcnt vmcnt(5)\n\ts_barrier" ::: "memory");
        } else {
            asm volatile("s_waitcnt vmcnt(0)\n\ts_barrier" ::: "memory");
        }
        if (it + 2 < 16) stage(it + 2);

        const unsigned Ab = sb + (unsigned)((it % 3) * 10240);
        const unsigned Bb = sb + 30720u + (unsigned)((it % 3) * 32768);
        short8 af[5], bf[8];
#pragma unroll
        for (int mt = 0; mt < 5; mt++) {
            int m = mg * 80 + mt * 16 + l15;
            unsigned off = Ab + (unsigned)(m * 64 + (aq ^ ((m >> 1) & 3)) * 16);
            asm volatile("ds_read_b128 %0, %1" : "=v"(af[mt]) : "v"(off));
        }
#pragma unroll
        for (int nt = 0; nt < 8; nt++) {
            int n = ng * 128 + nt * 16 + l15;
            unsigned off = Bb + (unsigned)(n * 64 + (aq ^ ((n >> 1) & 3)) * 16);
            asm volatile("ds_read_b128 %0, %1" : "=v"(bf[nt]) : "v"(off));
        }
        asm volatile("s_waitcnt lgkmcnt(0)"
                     : "+v"(af[0]), "+v"(af[1]), "+v"(af[2]), "+v"(af[3]), "+v"(af[4]),
                       "+v"(bf[0]), "+v"(bf[1]), "+v"(bf[2]), "+v"(bf[3]),
                       "+v"(bf[4]), "+v"(bf[5]), "+v"(bf[6]), "+v"(bf[7]) :: "memory");
#pragma unroll
        for (int nt = 0; nt < 8; nt++)
#pragma unroll
            for (int mt = 0; mt < 5; mt++)
                acc[mt][nt] = __builtin_amdgcn_mfma_f32_16x16x32_bf16(af[mt], bf[nt], acc[mt][nt], 0, 0, 0);
    }

    // ---- epilogue: bias + LayerNorm + fp8 store via byte LDS tile ----
    float bcol[8], gcol[8], shcol[8];
#pragma unroll
    for (int nt = 0; nt < 8; nt++) {
        int col = ng * 128 + nt * 16 + l15;
        bcol[nt]  = b2f(bia[col]);
        gcol[nt]  = b2f(gg[col]);
        shcol[nt] = b2f(sh[col]);
    }
#pragma unroll
    for (int mt = 0; mt < 5; mt++)
#pragma unroll
        for (int nt = 0; nt < 8; nt++)
#pragma unroll
            for (int r = 0; r < 4; r++) acc[mt][nt][r] += bcol[nt];

#pragma unroll
    for (int mt = 0; mt < 5; mt++)
#pragma unroll
        for (int r = 0; r < 4; r++) {
            float s = 0.f, q = 0.f;
#pragma unroll
            for (int nt = 0; nt < 8; nt++) { float x = acc[mt][nt][r]; s += x; q += x * x; }
#pragma unroll
            for (int off = 1; off < 16; off <<= 1) {
                s += __shfl_xor(s, off, 64);
                q += __shfl_xor(q, off, 64);
            }
            if (l15 == 0) {
                int row = mg * 80 + mt * 16 + aq * 4 + r;
                red[row][ng][0] = s;
                red[row][ng][1] = q;
            }
        }
    __syncthreads();   // red complete; also: all K-loop LDS reads done -> S reusable

    float mean_[5][4], rstd_[5][4];
#pragma unroll
    for (int mt = 0; mt < 5; mt++)
#pragma unroll
        for (int r = 0; r < 4; r++) {
            int row = mg * 80 + mt * 16 + aq * 4 + r;
            float s = red[row][0][0] + red[row][1][0] + red[row][2][0] + red[row][3][0];
            float q = red[row][0][1] + red[row][1][1] + red[row][2][1] + red[row][3][1];
            float mu  = s * (1.f / 512.f);
            float var = q * (1.f / 512.f) - mu * mu;
            mean_[mt][r] = mu;
            rstd_[mt][r] = rsqrtf(var + 1e-5f);
        }

    // fp8 values -> 160x528 byte tile (stride 528 = 16B-aligned), then coalesced stores
    unsigned char* ot8 = (unsigned char*)S;
#pragma unroll
    for (int mt = 0; mt < 5; mt++)
#pragma unroll
        for (int nt = 0; nt < 8; nt++)
#pragma unroll
            for (int r = 0; r < 4; r++) {
                int row = mg * 80 + mt * 16 + aq * 4 + r;
                int col = ng * 128 + nt * 16 + l15;
                float v = (acc[mt][nt][r] - mean_[mt][r]) * rstd_[mt][r] * gcol[nt] + shcol[nt];
                ot8[row * 528 + col] = f2fp8(v);
            }
    __syncthreads();

    unsigned char* obase = a12 + sel * 512;
#pragma unroll
    for (int u = 0; u < 10; u++) {
        int ci  = u * 512 + tid;             // 5120 chunks of 16 fp8
        int row = ci >> 5, cc = (ci & 31) * 16;
        int gr  = r0 + row;
        if (gr < M_ROWS) {
            uint4 vch = *(const uint4*)(ot8 + row * 528 + cc);
            *(uint4*)(obase + (size_t)gr * 1024 + cc) = vch;
        }
    }
}

// ---------------- per-edge: fp8 gather, packed-f16 Z dots, fused exp + segment sums ----
// v3: FOUR edges per wave (2 per half-wave, computed back-to-back). All 8 row-gathers
// issued before any compute; W3/index loads amortized; paired float2 stores.
// R4 result: only ~2us gain -> edge sits near the random-gather L2/L3 service
// ceiling (~148MB at ~3.2 TB/s); parked.
__global__ __launch_bounds__(256) void edge_k(
    const unsigned char* __restrict__ a12,   // fp8 rows: 1024 B/node
    const int* __restrict__ eidx,            // (B, 2, E)
    const unsigned short* __restrict__ W3h,  // f16[512]
    const unsigned short* __restrict__ W4,
    const unsigned short* __restrict__ b4p,
    float* __restrict__ Vij, float* __restrict__ Vji,
    float* __restrict__ sumI, float* __restrict__ sumJ)
{
    int wid   = (blockIdx.x * 256 + threadIdx.x) >> 6;  // wave id: 4 edges/wave
    int lane  = threadIdx.x & 63;
    int which = lane >> 5;                              // 0/1: edge-pair within wave
    int l     = lane & 31;
    int e0    = wid * 4 + which * 2;                    // this half-wave: edges e0, e0+1
    // grid is exact (BE/4 waves); e0, e0+1 never straddle the batch boundary (EE even)
    int b  = e0 / EE, ei = e0 - b * EE;
    const int* ebase = eidx + b * 2 * EE;
    int srcA = ebase[ei],      srcB = ebase[ei + 1];
    int dstA = ebase[EE + ei], dstB = ebase[EE + ei + 1];
    const unsigned char* nb = a12 + (size_t)(b * NN) * 1024;
    const unsigned char* rsA = nb + (size_t)srcA * 1024;
    const unsigned char* rdA = nb + (size_t)dstA * 1024;
    const unsigned char* rsB = nb + (size_t)srcB * 1024;
    const unsigned char* rdB = nb + (size_t)dstB * 1024;
    int o = l * 16;                                     // 16 fp8 elems per lane/vector

    // issue all 8 gathers (4/edge x 2 edges) up front: 2x MLP
    uint4 u1sA = *(const uint4*)(rsA + o);
    uint4 u2sA = *(const uint4*)(rsA + 512 + o);
    uint4 u1dA = *(const uint4*)(rdA + o);
    uint4 u2dA = *(const uint4*)(rdA + 512 + o);
    uint4 u1sB = *(const uint4*)(rsB + o);
    uint4 u2sB = *(const uint4*)(rsB + 512 + o);
    uint4 u1dB = *(const uint4*)(rdB + o);
    uint4 u2dB = *(const uint4*)(rdB + 512 + o);
    uint4 w3a = *(const uint4*)(W3h + l * 16);          // 16 f16 = 32B
    uint4 w3b = *(const uint4*)(W3h + l * 16 + 8);

    const unsigned int W3W[8] = {w3a.x, w3a.y, w3a.z, w3a.w, w3b.x, w3b.y, w3b.z, w3b.w};
    const half2v HZ = {(_Float16)0.f, (_Float16)0.f};

    float zijA = 0.f, zjiA = 0.f, zijB = 0.f, zjiB = 0.f;
#define EDGE_STEP(ZI, ZJ, V1S, V2S, V1D, V2D, WI, C, SEL)            \
    {                                                                \
        half2v wv  = uint2h2(W3W[WI]);                               \
        half2v x1s = CVT8H(V1S.C, SEL);                              \
        half2v x2s = CVT8H(V2S.C, SEL);                              \
        half2v x1d = CVT8H(V1D.C, SEL);                              \
        half2v x2d = CVT8H(V2D.C, SEL);                              \
        half2v pij = __builtin_elementwise_max(x1s + x2d, HZ);       \
        half2v pji = __builtin_elementwise_max(x1d + x2s, HZ);       \
        ZI = FDOT2(pij, wv, ZI);                                     \
        ZJ = FDOT2(pji, wv, ZJ);                                     \
    }
#define EDGE_ALL(ZI, ZJ, V1S, V2S, V1D, V2D)                         \
    EDGE_STEP(ZI, ZJ, V1S, V2S, V1D, V2D, 0, x, false)               \
    EDGE_STEP(ZI, ZJ, V1S, V2S, V1D, V2D, 1, x, true)                \
    EDGE_STEP(ZI, ZJ, V1S, V2S, V1D, V2D, 2, y, false)               \
    EDGE_STEP(ZI, ZJ, V1S, V2S, V1D, V2D, 3, y, true)                \
    EDGE_STEP(ZI, ZJ, V1S, V2S, V1D, V2D, 4, z, false)               \
    EDGE_STEP(ZI, ZJ, V1S, V2S, V1D, V2D, 5, z, true)                \
    EDGE_STEP(ZI, ZJ, V1S, V2S, V1D, V2D, 6, w, false)               \
    EDGE_STEP(ZI, ZJ, V1S, V2S, V1D, V2D, 7, w, true)

    EDGE_ALL(zijA, zjiA, u1sA, u2sA, u1dA, u2dA)
    EDGE_ALL(zijB, zjiB, u1sB, u2sB, u1dB, u2dB)
#undef EDGE_ALL
#undef EDGE_STEP

#pragma unroll
    for (int off = 16; off >= 1; off >>= 1) {           // reduce within each half-wave
        zijA += __shfl_xor(zijA, off, 64);
        zjiA += __shfl_xor(zjiA, off, 64);
        zijB += __shfl_xor(zijB, off, 64);
        zjiB += __shfl_xor(zjiB, off, 64);
    }
    if (l == 0) {                                       // lanes 0 and 32: one pair each
        float w4f = b2f(W4[0]);
        float b4f = b2f(b4p[0]);
        float dA   = zijA - zjiA;                       // b3 cancels exactly
        float vijA = fmaf(dA, w4f, b4f);  vijA = vijA > 0.f ? vijA : 0.f;
        float vjiA = fmaf(-dA, w4f, b4f); vjiA = vjiA > 0.f ? vjiA : 0.f;
        float dB   = zijB - zjiB;
        float vijB = fmaf(dB, w4f, b4f);  vijB = vijB > 0.f ? vijB : 0.f;
        float vjiB = fmaf(-dB, w4f, b4f); vjiB = vjiB > 0.f ? vjiB : 0.f;
        float eijA = expf(vijA), ejiA = expf(vjiA);
        float eijB = expf(vijB), ejiB = expf(vjiB);
        *(float2*)(Vij + e0) = (float2){eijA, eijB};    // e0 even -> aligned
        *(float2*)(Vji + e0) = (float2){ejiA, ejiB};
        atomicAdd(sumI + b * NN + srcA, eijA);
        atomicAdd(sumJ + b * NN + dstA, ejiA);
        atomicAdd(sumI + b * NN + srcB, eijB);
        atomicAdd(sumJ + b * NN + dstB, ejiB);
    }
}

// ---------------- softmax final: normalize -> bf16 or f32 out ----------------
__global__ __launch_bounds__(256) void norm_k(
    const float* __restrict__ V, const int* __restrict__ eidx,
    const float* __restrict__ sumI, const float* __restrict__ sumJ,
    const int* __restrict__ flag, void* __restrict__ out)
{
    int i = blockIdx.x * 256 + threadIdx.x;
    if (i >= 2 * BE) return;
    int seg; const float* sm;
    if (i < BE) {
        int b = i / EE, e = i - b * EE;
        seg = b * NN + eidx[b * 2 * EE + e];
        sm = sumI;
    } else {
        int j = i - BE;
        int b = j / EE, e = j - b * EE;
        seg = b * NN + eidx[b * 2 * EE + EE + e];
        sm = sumJ;
    }
    float v = V[i] / sm[seg];
    if (*flag) ((float*)out)[i] = v;
    else       ((unsigned short*)out)[i] = f2b(v);
}

extern "C" void kernel_launch(void* const* d_in, const int* in_sizes, int n_in,
                              void* d_out, int out_size, void* d_ws, size_t ws_size,
                              hipStream_t stream)
{
    (void)in_sizes; (void)n_in; (void)out_size; (void)ws_size;
    const void* X_raw = d_in[0];
    const int*  eix   = (const int*)d_in[1];
    const void* W1    = d_in[3];
    const void* b1    = d_in[4];
    const void* g1    = d_in[5];
    const void* bb1   = d_in[6];
    const void* W2    = d_in[7];
    const void* b2    = d_in[8];
    const void* g2    = d_in[9];
    const void* bb2   = d_in[10];
    const void* W3    = d_in[11];
    const void* W4    = d_in[13];
    const void* b4    = d_in[14];

    char* ws = (char*)d_ws;
    size_t off = 0;
    int* flag = (int*)(ws + off);                        off += 16;
    unsigned char*  a12 = (unsigned char*)(ws + off);    off += (size_t)M_ROWS * 1024;     // 20.48 MB fp8
    unsigned short* Xb  = (unsigned short*)(ws + off);   off += (size_t)M_PAD * 512 * 2;   // 20.6 MB
    unsigned short* T1  = (unsigned short*)(ws + off);   off += (size_t)512 * 512 * 2;
    unsigned short* T2  = (unsigned short*)(ws + off);   off += (size_t)512 * 512 * 2;
    unsigned short* P   = (unsigned short*)(ws + off);   off += 16384;                     // params + f16 W3
    float* Vbuf = (float*)(ws + off);                    off += (size_t)2 * BE * 4;
    float* Z    = (float*)(ws + off);                    off += (size_t)2 * BNN * 4;
    float* sumI = Z;
    float* sumJ = Z + BNN;

    prep_k<<<PREP_NB, 256, 0, stream>>>(X_raw, W1, W2, b1, g1, bb1, b2, g2, bb2,
                                        W3, W4, b4, flag, Xb, T1, T2, P, Z);
    gemm_ln7_k<<<dim3(126, 2), 512, 0, stream>>>((const unsigned short*)X_raw, Xb, flag,
                                                 T1, T2,
                                                 P, P + 512, P + 1024,
                                                 P + 1536, P + 2048, P + 2560, a12);
    edge_k<<<BE / 16, 256, 0, stream>>>(a12, eix, P + 3600, P + 3584, P + 3585,
                                        Vbuf, Vbuf + BE, sumI, sumJ);
    norm_k<<<(2 * BE + 255) / 256, 256, 0, stream>>>(Vbuf, eix, sumI, sumJ, flag, (unsigned short*)d_out);
}